// Round 24
// baseline (196.116 us; speedup 1.0000x reference)
//
#include <hip/hip_runtime.h>
#include <hip/hip_bf16.h>

// Problem constants (from reference source)
#define REGION_R0 42033
#define REGION_R1 44630
#define RN        (REGION_R1 - REGION_R0)   // 2597
#define CH        64
#define KSPLIT    32
#define ROW_TILES ((RN + 31) / 32)          // 82
#define SCAN_B    256
#define NSLICE    8
#define SLICE_RB  256                        // tier-2 grid

// bucket partition geometry
#define NB        64                         // range-blocks: 16-entry (64B) exclusive runs
#define T1        1024                       // 16 waves/block
#define MAXBUK    2048

// padded weight-LDS stride (floats per rel): 17 x float4 = 68 floats
#define WSTR      68

// MFMA region-gemm geometry
#define KTT       82
#define KP        (KTT * 32)                 // 2624
#define PERCHUNK  6
#define KCHUNKS   14
#define MT_TILES  163
#define MT_BLKS   41

typedef unsigned short ushort_t;
typedef short  bfrag8 __attribute__((ext_vector_type(8)));
typedef float  f32x4v __attribute__((ext_vector_type(4)));

// =========================================================================
// Region blend init (region_ent = 0.8 * orig)
// =========================================================================
__global__ void region_init_kernel(const float* __restrict__ emb,
                                   float* __restrict__ region_ent) {
    const int gid = blockIdx.x * blockDim.x + threadIdx.x;
    if (gid >= RN * CH / 4) return;
    const float4 v = reinterpret_cast<const float4*>(emb + (size_t)REGION_R0 * CH)[gid];
    float4 o;
    o.x = 0.8f * v.x; o.y = 0.8f * v.y; o.z = 0.8f * v.z; o.w = 0.8f * v.w;
    reinterpret_cast<float4*>(region_ent)[gid] = o;
}

__device__ __forceinline__ unsigned pack2bf(float a, float b) {
    unsigned ua = __float_as_uint(a);
    unsigned ub = __float_as_uint(b);
    ua += 0x7fffu + ((ua >> 16) & 1u);   // RNE
    ub += 0x7fffu + ((ub >> 16) & 1u);
    return ((ua >> 16) & 0xffffu) | (ub & 0xffff0000u);
}

// =========================================================================
// e_t[c][k] = bf16(emb[R0+k][c]) (B operand, transposed, zero-padded)
// =========================================================================
__global__ void build_et_kernel(const float* __restrict__ emb,
                                ushort_t* __restrict__ e_t) {
    const int gid = blockIdx.x * blockDim.x + threadIdx.x;
    if (gid >= CH * (KP / 8)) return;
    const int c  = gid / (KP / 8);
    const int k8 = gid - c * (KP / 8);
    const int kb = k8 * 8;
    float v[8];
#pragma unroll
    for (int j = 0; j < 8; ++j) {
        const int k = kb + j;
        v[j] = (k < RN) ? emb[(size_t)(REGION_R0 + k) * CH + c] : 0.0f;
    }
    uint4 o;
    o.x = pack2bf(v[0], v[1]); o.y = pack2bf(v[2], v[3]);
    o.z = pack2bf(v[4], v[5]); o.w = pack2bf(v[6], v[7]);
    *reinterpret_cast<uint4*>(e_t + (size_t)c * KP + kb) = o;
}

// =========================================================================
// MFMA region GEMM (R14-verified, absmax 0.25)
// =========================================================================
__global__ void region_gemm_mfma_kernel(const float* __restrict__ W,
                                        const ushort_t* __restrict__ e_t,
                                        float* __restrict__ region_ent) {
    const int wv    = threadIdx.x >> 6;
    const int lane  = threadIdx.x & 63;
    const int blk_m = blockIdx.x / KCHUNKS;
    const int kc    = blockIdx.x - blk_m * KCHUNKS;
    const int mt    = blk_m * 4 + wv;
    if (mt >= MT_TILES) return;
    const int l15 = lane & 15;
    const int lg  = lane >> 4;

    int arow = mt * 16 + l15;
    if (arow >= RN) arow = RN - 1;
    const float* wrow = W + (size_t)arow * RN;

    const int kt0 = kc * PERCHUNK;
    const int kt1 = (kt0 + PERCHUNK < KTT) ? (kt0 + PERCHUNK) : KTT;

    f32x4v acc[4];
#pragma unroll
    for (int n = 0; n < 4; ++n) acc[n] = (f32x4v){0.f, 0.f, 0.f, 0.f};

    for (int kt = kt0; kt < kt1; ++kt) {
        const int kb = kt * 32 + lg * 8;
        union { uint4 u; bfrag8 f; } A;
        if (kb + 8 <= RN) {
            float v0 = wrow[kb + 0], v1 = wrow[kb + 1];
            float v2 = wrow[kb + 2], v3 = wrow[kb + 3];
            float v4 = wrow[kb + 4], v5 = wrow[kb + 5];
            float v6 = wrow[kb + 6], v7 = wrow[kb + 7];
            A.u.x = pack2bf(v0, v1); A.u.y = pack2bf(v2, v3);
            A.u.z = pack2bf(v4, v5); A.u.w = pack2bf(v6, v7);
        } else {
            float v[8];
#pragma unroll
            for (int j = 0; j < 8; ++j) {
                const int k = kb + j;
                v[j] = (k < RN) ? wrow[k] : 0.0f;
            }
            A.u.x = pack2bf(v[0], v[1]); A.u.y = pack2bf(v[2], v[3]);
            A.u.z = pack2bf(v[4], v[5]); A.u.w = pack2bf(v[6], v[7]);
        }
#pragma unroll
        for (int n = 0; n < 4; ++n) {
            const bfrag8 B = *reinterpret_cast<const bfrag8*>(
                e_t + (size_t)(n * 16 + l15) * KP + kb);
            acc[n] = __builtin_amdgcn_mfma_f32_16x16x32_bf16(A.f, B, acc[n], 0, 0, 0);
        }
    }

#pragma unroll
    for (int n = 0; n < 4; ++n) {
#pragma unroll
        for (int j = 0; j < 4; ++j) {
            const int row = mt * 16 + lg * 4 + j;
            if (row < RN)
                unsafeAtomicAdd(region_ent + (size_t)row * CH + n * 16 + l15,
                                0.2f * acc[n][j]);
        }
    }
}

// =========================================================================
// VALU region GEMM (tier-3 fallback only)
// =========================================================================
__global__ void region_gemm_kernel(const float* __restrict__ emb,
                                   const float* __restrict__ W,
                                   float* __restrict__ region_ent) {
    const int wave = threadIdx.x >> 6;
    const int c    = threadIdx.x & 63;
    const int rt   = blockIdx.x / KSPLIT;
    const int ks   = blockIdx.x - rt * KSPLIT;
    const int base = rt * 32 + wave * 8;
    if (base >= RN) return;

    const int k0 = (RN * ks) / KSPLIT;
    const int k1 = (RN * (ks + 1)) / KSPLIT;

    const float* wp[8];
#pragma unroll
    for (int r = 0; r < 8; ++r) {
        int row = base + r;
        if (row >= RN) row = RN - 1;
        row = __builtin_amdgcn_readfirstlane(row);
        wp[r] = W + (size_t)row * RN;
    }
    const float* ep = emb + (size_t)REGION_R0 * CH + c;

    float acc[8];
#pragma unroll
    for (int r = 0; r < 8; ++r) acc[r] = 0.0f;

    int k = k0;
    for (; k + 4 <= k1; k += 4) {
        const float e0 = ep[(size_t)(k + 0) * CH];
        const float e1 = ep[(size_t)(k + 1) * CH];
        const float e2 = ep[(size_t)(k + 2) * CH];
        const float e3 = ep[(size_t)(k + 3) * CH];
#pragma unroll
        for (int r = 0; r < 8; ++r) {
            const float* wr = wp[r];
            float a = acc[r];
            a = fmaf(wr[k + 0], e0, a);
            a = fmaf(wr[k + 1], e1, a);
            a = fmaf(wr[k + 2], e2, a);
            a = fmaf(wr[k + 3], e3, a);
            acc[r] = a;
        }
    }
    for (; k < k1; ++k) {
        const float e = ep[(size_t)k * CH];
#pragma unroll
        for (int r = 0; r < 8; ++r) acc[r] = fmaf(wp[r][k], e, acc[r]);
    }
#pragma unroll
    for (int r = 0; r < 8; ++r) {
        const int row = base + r;
        if (row < RN)
            unsafeAtomicAdd(region_ent + (size_t)row * CH + c, 0.2f * acc[r]);
    }
}

__device__ __forceinline__ float ent_val(const float* __restrict__ emb,
                                         const float* __restrict__ region_ent,
                                         int row, int c) {
    const float* p = (row >= REGION_R0 && row < REGION_R1)
                         ? (region_ent + (size_t)(row - REGION_R0) * CH + c)
                         : (emb + (size_t)row * CH + c);
    return *p;
}

__device__ __forceinline__ const float* ent_row(const float* __restrict__ emb,
                                                const float* __restrict__ region_ent,
                                                int row) {
    return (row >= REGION_R0 && row < REGION_R1)
               ? (region_ent + (size_t)(row - REGION_R0) * CH)
               : (emb + (size_t)row * CH);
}

// =========================================================================
// bf16 entity table (region rows baked in)
// =========================================================================
__global__ void build_ebf_kernel(const float* __restrict__ emb,
                                 const float* __restrict__ region_ent,
                                 ushort_t* __restrict__ ebf,
                                 int n_entities) {
    const int gid = blockIdx.x * blockDim.x + threadIdx.x;
    if (gid >= n_entities * (CH / 8)) return;
    const int row = gid >> 3;
    const int co  = (gid & 7) * 8;
    const float* rp = ent_row(emb, region_ent, row) + co;
    const float4 a = *reinterpret_cast<const float4*>(rp);
    const float4 b = *reinterpret_cast<const float4*>(rp + 4);
    uint4 o;
    o.x = pack2bf(a.x, a.y);
    o.y = pack2bf(a.z, a.w);
    o.z = pack2bf(b.x, b.y);
    o.w = pack2bf(b.z, b.w);
    *reinterpret_cast<uint4*>(ebf + (size_t)row * CH + co) = o;
}

__device__ __forceinline__ float bf_lo(unsigned u) { return __uint_as_float(u << 16); }
__device__ __forceinline__ float bf_hi(unsigned u) { return __uint_as_float(u & 0xffff0000u); }

// =========================================================================
// Combined bucket hist (R23-proven: x4 unrolled key loads)
// =========================================================================
__global__ void bucket_hist2_kernel(const int* __restrict__ ekeys, int ne, int nbe,
                                    const int* __restrict__ ukeys, int nu, int nbu,
                                    int* __restrict__ hist_e,
                                    int* __restrict__ hist_u) {
    __shared__ int lh[MAXBUK];
    const bool is_u = (blockIdx.x >= NB);
    const int  rb   = is_u ? (blockIdx.x - NB) : blockIdx.x;
    const int* keys = is_u ? ukeys : ekeys;
    const int  n    = is_u ? nu : ne;
    const int  nbuk = is_u ? nbu : nbe;
    int* hist       = is_u ? hist_u : hist_e;

    for (int i = threadIdx.x; i < nbuk; i += T1) lh[i] = 0;
    __syncthreads();
    const int chunk = (n + NB - 1) / NB;
    const int i0 = rb * chunk;
    const int i1 = min(i0 + chunk, n);
    int i = i0 + (int)threadIdx.x;
    for (; i + 3 * T1 < i1; i += 4 * T1) {
        const int k0 = keys[i];
        const int k1 = keys[i + T1];
        const int k2 = keys[i + 2 * T1];
        const int k3 = keys[i + 3 * T1];
        atomicAdd(&lh[k0 >> 6], 1);
        atomicAdd(&lh[k1 >> 6], 1);
        atomicAdd(&lh[k2 >> 6], 1);
        atomicAdd(&lh[k3 >> 6], 1);
    }
    for (; i < i1; i += T1)
        atomicAdd(&lh[keys[i] >> 6], 1);
    __syncthreads();
    for (int b = threadIdx.x; b < nbuk; b += T1)
        hist[(size_t)b * NB + rb] = lh[b];
}

__global__ void scan_block_kernel(const int* __restrict__ counts, int* __restrict__ offs,
                                  int* __restrict__ bsums, int n) {
    __shared__ int s[SCAN_B];
    const int i = blockIdx.x * SCAN_B + threadIdx.x;
    s[threadIdx.x] = (i < n) ? counts[i] : 0;
    __syncthreads();
    for (int d = 1; d < SCAN_B; d <<= 1) {
        const int t = (threadIdx.x >= d) ? s[threadIdx.x - d] : 0;
        __syncthreads();
        s[threadIdx.x] += t;
        __syncthreads();
    }
    if (i < n) offs[i + 1] = s[threadIdx.x];
    if (threadIdx.x == SCAN_B - 1) bsums[blockIdx.x] = s[threadIdx.x];
    if (blockIdx.x == 0 && threadIdx.x == 0) offs[0] = 0;
}

__global__ void scan_top_kernel(int* __restrict__ bsums, int nb) {
    __shared__ int s[512];
    s[threadIdx.x] = (threadIdx.x < (unsigned)nb) ? bsums[threadIdx.x] : 0;
    __syncthreads();
    for (int d = 1; d < 512; d <<= 1) {
        const int t = (threadIdx.x >= d) ? s[threadIdx.x - d] : 0;
        __syncthreads();
        s[threadIdx.x] += t;
        __syncthreads();
    }
    if (threadIdx.x < (unsigned)nb) bsums[threadIdx.x] = s[threadIdx.x];
}

__global__ void scan_add_kernel(int* __restrict__ offs, const int* __restrict__ bsums, int n) {
    if (blockIdx.x == 0) return;
    const int i = blockIdx.x * SCAN_B + threadIdx.x;
    if (i < n) offs[i + 1] += bsums[blockIdx.x - 1];
}

// =========================================================================
// Combined pass2 (R23-proven: x4 unrolled chains)
// =========================================================================
__global__ void pass2_combined_kernel(const int* __restrict__ edge_index,
                                      const int* __restrict__ edge_type,
                                      const int* __restrict__ exbase_e,
                                      int* __restrict__ pcode_e,
                                      int E, int n_rel, int nbe,
                                      const int* __restrict__ irows,
                                      const int* __restrict__ icols,
                                      const float* __restrict__ ivals,
                                      const int* __restrict__ exbase_u,
                                      uint2* __restrict__ pcode_u,
                                      int NNZ, int nbu) {
    __shared__ int cur[MAXBUK];
    __shared__ int exb[MAXBUK];
    const bool is_u = (blockIdx.x >= NB);
    const int  rb   = is_u ? (blockIdx.x - NB) : blockIdx.x;
    const int  nbuk = is_u ? nbu : nbe;
    const int* exbase = is_u ? exbase_u : exbase_e;

    for (int i = threadIdx.x; i < nbuk; i += T1) {
        cur[i] = 0;
        exb[i] = exbase[(size_t)i * NB + rb];
    }
    __syncthreads();

    if (!is_u) {
        const int chunk = (E + NB - 1) / NB;
        const int i0 = rb * chunk;
        const int i1 = min(i0 + chunk, E);
        int e = i0 + (int)threadIdx.x;
        for (; e + 3 * T1 < i1; e += 4 * T1) {
            const int h0 = edge_index[e];
            const int h1 = edge_index[e + T1];
            const int h2 = edge_index[e + 2 * T1];
            const int h3 = edge_index[e + 3 * T1];
            const int t0 = edge_index[(size_t)E + e];
            const int t1 = edge_index[(size_t)E + e + T1];
            const int t2 = edge_index[(size_t)E + e + 2 * T1];
            const int t3 = edge_index[(size_t)E + e + 3 * T1];
            int r0 = edge_type[e] - 1;             if (r0 < 0) r0 += n_rel;
            int r1 = edge_type[e + T1] - 1;        if (r1 < 0) r1 += n_rel;
            int r2 = edge_type[e + 2 * T1] - 1;    if (r2 < 0) r2 += n_rel;
            int r3 = edge_type[e + 3 * T1] - 1;    if (r3 < 0) r3 += n_rel;
            const int b0 = h0 >> 6, b1 = h1 >> 6, b2 = h2 >> 6, b3 = h3 >> 6;
            const int l0 = atomicAdd(&cur[b0], 1);
            const int l1 = atomicAdd(&cur[b1], 1);
            const int l2 = atomicAdd(&cur[b2], 1);
            const int l3 = atomicAdd(&cur[b3], 1);
            pcode_e[exb[b0] + l0] = ((h0 & 63) << 22) | (r0 << 17) | t0;
            pcode_e[exb[b1] + l1] = ((h1 & 63) << 22) | (r1 << 17) | t1;
            pcode_e[exb[b2] + l2] = ((h2 & 63) << 22) | (r2 << 17) | t2;
            pcode_e[exb[b3] + l3] = ((h3 & 63) << 22) | (r3 << 17) | t3;
        }
        for (; e < i1; e += T1) {
            const int h = edge_index[e];
            const int b = h >> 6;
            const int loc = atomicAdd(&cur[b], 1);
            const int pos = exb[b] + loc;
            const int t = edge_index[(size_t)E + e];
            int r = edge_type[e] - 1;
            if (r < 0) r += n_rel;
            pcode_e[pos] = ((h & 63) << 22) | (r << 17) | t;
        }
    } else {
        const int chunk = (NNZ + NB - 1) / NB;
        const int i0 = rb * chunk;
        const int i1 = min(i0 + chunk, NNZ);
        int i = i0 + (int)threadIdx.x;
        for (; i + 3 * T1 < i1; i += 4 * T1) {
            const int u0 = irows[i];
            const int u1 = irows[i + T1];
            const int u2 = irows[i + 2 * T1];
            const int u3 = irows[i + 3 * T1];
            const int c0 = icols[i];
            const int c1 = icols[i + T1];
            const int c2 = icols[i + 2 * T1];
            const int c3 = icols[i + 3 * T1];
            const float v0 = ivals[i];
            const float v1 = ivals[i + T1];
            const float v2 = ivals[i + 2 * T1];
            const float v3 = ivals[i + 3 * T1];
            const int b0 = u0 >> 6, b1 = u1 >> 6, b2 = u2 >> 6, b3 = u3 >> 6;
            const int l0 = atomicAdd(&cur[b0], 1);
            const int l1 = atomicAdd(&cur[b1], 1);
            const int l2 = atomicAdd(&cur[b2], 1);
            const int l3 = atomicAdd(&cur[b3], 1);
            uint2 cv;
            cv.x = ((unsigned)(u0 & 63) << 17) | (unsigned)c0;
            cv.y = __float_as_uint(v0);
            pcode_u[exb[b0] + l0] = cv;
            cv.x = ((unsigned)(u1 & 63) << 17) | (unsigned)c1;
            cv.y = __float_as_uint(v1);
            pcode_u[exb[b1] + l1] = cv;
            cv.x = ((unsigned)(u2 & 63) << 17) | (unsigned)c2;
            cv.y = __float_as_uint(v2);
            pcode_u[exb[b2] + l2] = cv;
            cv.x = ((unsigned)(u3 & 63) << 17) | (unsigned)c3;
            cv.y = __float_as_uint(v3);
            pcode_u[exb[b3] + l3] = cv;
        }
        for (; i < i1; i += T1) {
            const int u = irows[i];
            const int b = u >> 6;
            const int loc = atomicAdd(&cur[b], 1);
            const int pos = exb[b] + loc;
            uint2 cv;
            cv.x = ((unsigned)(u & 63) << 17) | (unsigned)icols[i];
            cv.y = __float_as_uint(ivals[i]);
            pcode_u[pos] = cv;
        }
    }
}

// =========================================================================
// Combined per-bucket counting sort (R20-proven)
// =========================================================================
__global__ void bucket_sort2_kernel(const int* __restrict__ pcode_e,
                                    const int* __restrict__ exbase_e,
                                    int* __restrict__ sorted_tr,
                                    int* __restrict__ offs_e,
                                    int n_entities, int nbe,
                                    const uint2* __restrict__ pcode_u,
                                    const int* __restrict__ exbase_u,
                                    uint2* __restrict__ upack,
                                    int* __restrict__ offs_u,
                                    int n_users, int nbu) {
    __shared__ int cnt[64];
    __shared__ int off[64];
    __shared__ int cur[64];
    const bool is_u = (blockIdx.x >= (unsigned)nbe);
    const int  b    = is_u ? (blockIdx.x - nbe) : blockIdx.x;
    const int* exbase = is_u ? exbase_u : exbase_e;
    const int bstart = exbase[(size_t)b * NB];
    const int bend   = exbase[(size_t)(b + 1) * NB];
    if (threadIdx.x < 64) { cnt[threadIdx.x] = 0; cur[threadIdx.x] = 0; }
    __syncthreads();

    if (!is_u) {
        for (int i = bstart + (int)threadIdx.x; i < bend; i += blockDim.x)
            atomicAdd(&cnt[(pcode_e[i] >> 22) & 63], 1);
    } else {
        for (int i = bstart + (int)threadIdx.x; i < bend; i += blockDim.x)
            atomicAdd(&cnt[(pcode_u[i].x >> 17) & 63], 1);
    }
    __syncthreads();
    if (threadIdx.x == 0) {
        int s = 0;
#pragma unroll
        for (int i = 0; i < 64; ++i) { off[i] = s; s += cnt[i]; }
    }
    __syncthreads();

    if (!is_u) {
        const int h0 = b * 64;
        if (threadIdx.x < 64) {
            const int h = h0 + (int)threadIdx.x;
            if (h < n_entities) offs_e[h] = bstart + off[threadIdx.x];
        }
        if (b == nbe - 1 && threadIdx.x == 0) offs_e[n_entities] = bend;
        for (int i = bstart + (int)threadIdx.x; i < bend; i += blockDim.x) {
            const int p  = pcode_e[i];
            const int lh = (p >> 22) & 63;
            const int pos = bstart + off[lh] + atomicAdd(&cur[lh], 1);
            sorted_tr[pos] = p & 0x3FFFFF;
        }
    } else {
        const int u0 = b * 64;
        if (threadIdx.x < 64) {
            const int u = u0 + (int)threadIdx.x;
            if (u < n_users) offs_u[u] = bstart + off[threadIdx.x];
        }
        if (b == nbu - 1 && threadIdx.x == 0) offs_u[n_users] = bend;
        for (int i = bstart + (int)threadIdx.x; i < bend; i += blockDim.x) {
            const uint2 cv = pcode_u[i];
            const int lr = (int)(cv.x >> 17) & 63;
            const int pos = bstart + off[lr] + atomicAdd(&cur[lr], 1);
            uint2 o;
            o.x = cv.x & 0x1FFFFu;
            o.y = cv.y;
            upack[pos] = o;
        }
    }
}

// =========================================================================
// bf16 gather kernels v3 + R24: padded weight LDS (stride WSTR=68 floats)
// kills the 8-way bank conflict (bank = (4*rel + 8*q8) % 32).
// =========================================================================
__global__ void kg_gather_bf_kernel(const ushort_t* __restrict__ ebf,
                                    const int* __restrict__ sorted_tr,
                                    const int* __restrict__ offs,
                                    const float* __restrict__ weight,
                                    float* __restrict__ out_ent,
                                    int n_entities, int n_rel) {
    extern __shared__ float wl[];   // n_rel * WSTR floats (padded)
    for (int i = threadIdx.x; i < n_rel * CH; i += blockDim.x) {
        const int r = i >> 6;
        const int c = i & 63;
        wl[r * WSTR + c] = weight[i];
    }
    __syncthreads();

    const int wid  = (blockIdx.x * blockDim.x + threadIdx.x) >> 6;
    const int lane = threadIdx.x & 63;
    const int g    = lane >> 3;     // edge slot 0..7
    const int q8   = lane & 7;      // channel octet 0..7
    if (wid >= n_entities) return;

    const int s0 = offs[wid], s1 = offs[wid + 1];
    float a0[8], a1[8];
#pragma unroll
    for (int j = 0; j < 8; ++j) { a0[j] = 0.f; a1[j] = 0.f; }

    int base = s0;
    for (; base + 16 <= s1; base += 16) {
        const int tr0 = sorted_tr[base + g];
        const int tr1 = sorted_tr[base + 8 + g];
        const uint4 p0 = *reinterpret_cast<const uint4*>(
            ebf + (size_t)(tr0 & 0x1FFFF) * CH + q8 * 8);
        const uint4 p1 = *reinterpret_cast<const uint4*>(
            ebf + (size_t)(tr1 & 0x1FFFF) * CH + q8 * 8);
        const float* w0p = wl + (tr0 >> 17) * WSTR + q8 * 8;
        const float* w1p = wl + (tr1 >> 17) * WSTR + q8 * 8;
        const float4 w0a = *reinterpret_cast<const float4*>(w0p);
        const float4 w0b = *reinterpret_cast<const float4*>(w0p + 4);
        const float4 w1a = *reinterpret_cast<const float4*>(w1p);
        const float4 w1b = *reinterpret_cast<const float4*>(w1p + 4);
        a0[0] = fmaf(bf_lo(p0.x), w0a.x, a0[0]);
        a0[1] = fmaf(bf_hi(p0.x), w0a.y, a0[1]);
        a0[2] = fmaf(bf_lo(p0.y), w0a.z, a0[2]);
        a0[3] = fmaf(bf_hi(p0.y), w0a.w, a0[3]);
        a0[4] = fmaf(bf_lo(p0.z), w0b.x, a0[4]);
        a0[5] = fmaf(bf_hi(p0.z), w0b.y, a0[5]);
        a0[6] = fmaf(bf_lo(p0.w), w0b.z, a0[6]);
        a0[7] = fmaf(bf_hi(p0.w), w0b.w, a0[7]);
        a1[0] = fmaf(bf_lo(p1.x), w1a.x, a1[0]);
        a1[1] = fmaf(bf_hi(p1.x), w1a.y, a1[1]);
        a1[2] = fmaf(bf_lo(p1.y), w1a.z, a1[2]);
        a1[3] = fmaf(bf_hi(p1.y), w1a.w, a1[3]);
        a1[4] = fmaf(bf_lo(p1.z), w1b.x, a1[4]);
        a1[5] = fmaf(bf_hi(p1.z), w1b.y, a1[5]);
        a1[6] = fmaf(bf_lo(p1.w), w1b.z, a1[6]);
        a1[7] = fmaf(bf_hi(p1.w), w1b.w, a1[7]);
    }
    for (; base < s1; base += 8) {
        const int e = base + g;
        const bool valid = (e < s1);
        const int tr = valid ? sorted_tr[e] : 0;
        uint4 p; p.x = 0u; p.y = 0u; p.z = 0u; p.w = 0u;
        if (valid)
            p = *reinterpret_cast<const uint4*>(
                ebf + (size_t)(tr & 0x1FFFF) * CH + q8 * 8);
        const float* wp = wl + (tr >> 17) * WSTR + q8 * 8;
        const float4 wa = *reinterpret_cast<const float4*>(wp);
        const float4 wb = *reinterpret_cast<const float4*>(wp + 4);
        a0[0] = fmaf(bf_lo(p.x), wa.x, a0[0]);
        a0[1] = fmaf(bf_hi(p.x), wa.y, a0[1]);
        a0[2] = fmaf(bf_lo(p.y), wa.z, a0[2]);
        a0[3] = fmaf(bf_hi(p.y), wa.w, a0[3]);
        a0[4] = fmaf(bf_lo(p.z), wb.x, a0[4]);
        a0[5] = fmaf(bf_hi(p.z), wb.y, a0[5]);
        a0[6] = fmaf(bf_lo(p.w), wb.z, a0[6]);
        a0[7] = fmaf(bf_hi(p.w), wb.w, a0[7]);
    }
#pragma unroll
    for (int j = 0; j < 8; ++j) a0[j] += a1[j];

#pragma unroll
    for (int j = 0; j < 8; ++j) {
        a0[j] += __shfl_xor(a0[j], 8);
        a0[j] += __shfl_xor(a0[j], 16);
        a0[j] += __shfl_xor(a0[j], 32);
    }

    if (g == 0) {
        const int deg = s1 - s0;
        const float inv = 1.0f / (float)(deg > 0 ? deg : 1);
        float4 o0, o1;
        o0.x = a0[0] * inv; o0.y = a0[1] * inv; o0.z = a0[2] * inv; o0.w = a0[3] * inv;
        o1.x = a0[4] * inv; o1.y = a0[5] * inv; o1.z = a0[6] * inv; o1.w = a0[7] * inv;
        float* op = out_ent + (size_t)wid * CH + q8 * 8;
        *reinterpret_cast<float4*>(op)     = o0;
        *reinterpret_cast<float4*>(op + 4) = o1;
    }
}

__global__ void user_gather_bf_kernel(const ushort_t* __restrict__ ebf,
                                      const uint2* __restrict__ upack,
                                      const int* __restrict__ offs,
                                      float* __restrict__ out_user,
                                      int n_users) {
    const int wid  = (blockIdx.x * blockDim.x + threadIdx.x) >> 6;
    const int lane = threadIdx.x & 63;
    const int g    = lane >> 3;
    const int q8   = lane & 7;
    if (wid >= n_users) return;

    const int s0 = offs[wid], s1 = offs[wid + 1];
    float a0[8], a1[8];
#pragma unroll
    for (int j = 0; j < 8; ++j) { a0[j] = 0.f; a1[j] = 0.f; }

    int base = s0;
    for (; base + 16 <= s1; base += 16) {
        const uint2 cv0 = upack[base + g];
        const uint2 cv1 = upack[base + 8 + g];
        const float v0 = __uint_as_float(cv0.y);
        const float v1 = __uint_as_float(cv1.y);
        const uint4 p0 = *reinterpret_cast<const uint4*>(
            ebf + (size_t)cv0.x * CH + q8 * 8);
        const uint4 p1 = *reinterpret_cast<const uint4*>(
            ebf + (size_t)cv1.x * CH + q8 * 8);
        a0[0] = fmaf(v0, bf_lo(p0.x), a0[0]);
        a0[1] = fmaf(v0, bf_hi(p0.x), a0[1]);
        a0[2] = fmaf(v0, bf_lo(p0.y), a0[2]);
        a0[3] = fmaf(v0, bf_hi(p0.y), a0[3]);
        a0[4] = fmaf(v0, bf_lo(p0.z), a0[4]);
        a0[5] = fmaf(v0, bf_hi(p0.z), a0[5]);
        a0[6] = fmaf(v0, bf_lo(p0.w), a0[6]);
        a0[7] = fmaf(v0, bf_hi(p0.w), a0[7]);
        a1[0] = fmaf(v1, bf_lo(p1.x), a1[0]);
        a1[1] = fmaf(v1, bf_hi(p1.x), a1[1]);
        a1[2] = fmaf(v1, bf_lo(p1.y), a1[2]);
        a1[3] = fmaf(v1, bf_hi(p1.y), a1[3]);
        a1[4] = fmaf(v1, bf_lo(p1.z), a1[4]);
        a1[5] = fmaf(v1, bf_hi(p1.z), a1[5]);
        a1[6] = fmaf(v1, bf_lo(p1.w), a1[6]);
        a1[7] = fmaf(v1, bf_hi(p1.w), a1[7]);
    }
    for (; base < s1; base += 8) {
        const int e = base + g;
        const bool valid = (e < s1);
        uint2 cv; cv.x = 0u; cv.y = 0u;
        if (valid) cv = upack[e];
        const float v = __uint_as_float(cv.y);   // 0 when invalid
        const uint4 p = *reinterpret_cast<const uint4*>(
            ebf + (size_t)cv.x * CH + q8 * 8);   // row 0 valid memory
        a0[0] = fmaf(v, bf_lo(p.x), a0[0]);
        a0[1] = fmaf(v, bf_hi(p.x), a0[1]);
        a0[2] = fmaf(v, bf_lo(p.y), a0[2]);
        a0[3] = fmaf(v, bf_hi(p.y), a0[3]);
        a0[4] = fmaf(v, bf_lo(p.z), a0[4]);
        a0[5] = fmaf(v, bf_hi(p.z), a0[5]);
        a0[6] = fmaf(v, bf_lo(p.w), a0[6]);
        a0[7] = fmaf(v, bf_hi(p.w), a0[7]);
    }
#pragma unroll
    for (int j = 0; j < 8; ++j) a0[j] += a1[j];

#pragma unroll
    for (int j = 0; j < 8; ++j) {
        a0[j] += __shfl_xor(a0[j], 8);
        a0[j] += __shfl_xor(a0[j], 16);
        a0[j] += __shfl_xor(a0[j], 32);
    }

    if (g == 0) {
        float4 o0, o1;
        o0.x = a0[0]; o0.y = a0[1]; o0.z = a0[2]; o0.w = a0[3];
        o1.x = a0[4]; o1.y = a0[5]; o1.z = a0[6]; o1.w = a0[7];
        float* op = out_user + (size_t)wid * CH + q8 * 8;
        *reinterpret_cast<float4*>(op)     = o0;
        *reinterpret_cast<float4*>(op + 4) = o1;
    }
}

// =========================================================================
// Tier-2 (R14 CSR path): sliced hist/scatter
// =========================================================================
__global__ void hist_sliced_kernel(const int* __restrict__ keys,
                                   int* __restrict__ counts, int n, unsigned smul) {
    const int slice = blockIdx.x & (NSLICE - 1);
    const int rb    = blockIdx.x >> 3;
    const int nrb   = gridDim.x >> 3;
    const int per   = (n + nrb - 1) / nrb;
    const int i0    = rb * per;
    const int i1    = min(i0 + per, n);
    for (int i = i0 + (int)threadIdx.x; i < i1; i += blockDim.x) {
        const int k = keys[i];
        if ((int)__umulhi((unsigned)k, smul) == slice)
            atomicAdd(&counts[k], 1);
    }
}

__global__ void scatter_e_sliced_kernel(const int* __restrict__ edge_index,
                                        const int* __restrict__ edge_type,
                                        const int* __restrict__ offs,
                                        int* __restrict__ cursor,
                                        int* __restrict__ sorted_tr,
                                        int E, int n_rel, unsigned smul) {
    const int slice = blockIdx.x & (NSLICE - 1);
    const int rb    = blockIdx.x >> 3;
    const int nrb   = gridDim.x >> 3;
    const int per   = (E + nrb - 1) / nrb;
    const int e0    = rb * per;
    const int e1    = min(e0 + per, E);
    for (int e = e0 + (int)threadIdx.x; e < e1; e += blockDim.x) {
        const int h = edge_index[e];
        if ((int)__umulhi((unsigned)h, smul) != slice) continue;
        const int t = edge_index[(size_t)E + e];
        int r = edge_type[e] - 1;
        if (r < 0) r += n_rel;
        const int pos = offs[h] + atomicAdd(&cursor[h], 1);
        sorted_tr[pos] = t | (r << 17);
    }
}

__global__ void scatter_u_sliced_kernel(const int* __restrict__ irows,
                                        const int* __restrict__ icols,
                                        const float* __restrict__ ivals,
                                        const int* __restrict__ offs,
                                        int* __restrict__ cursor,
                                        uint2* __restrict__ upack,
                                        int NNZ, unsigned smul) {
    const int slice = blockIdx.x & (NSLICE - 1);
    const int rb    = blockIdx.x >> 3;
    const int nrb   = gridDim.x >> 3;
    const int per   = (NNZ + nrb - 1) / nrb;
    const int i0    = rb * per;
    const int i1    = min(i0 + per, NNZ);
    for (int i = i0 + (int)threadIdx.x; i < i1; i += blockDim.x) {
        const int u = irows[i];
        if ((int)__umulhi((unsigned)u, smul) != slice) continue;
        const int pos = offs[u] + atomicAdd(&cursor[u], 1);
        uint2 cv;
        cv.x = (unsigned)icols[i];
        cv.y = __float_as_uint(ivals[i]);
        upack[pos] = cv;
    }
}

// =========================================================================
// Tier-3 (atomic fallback)
// =========================================================================
__global__ void kg_agg_atomic_kernel(const float* __restrict__ emb,
                                     const float* __restrict__ region_ent,
                                     const int* __restrict__ edge_index,
                                     const int* __restrict__ edge_type,
                                     const float* __restrict__ weight,
                                     float* __restrict__ out_ent,
                                     float* __restrict__ counts,
                                     int E, int n_rel) {
    const long long gid = (long long)blockIdx.x * blockDim.x + threadIdx.x;
    const long long e = gid >> 6;
    if (e >= E) return;
    const int c = (int)gid & 63;
    const int h = edge_index[e];
    const int t = edge_index[(size_t)E + e];
    int r = edge_type[e] - 1;
    if (r < 0) r += n_rel;
    const float v = ent_val(emb, region_ent, t, c) * weight[(size_t)r * CH + c];
    unsafeAtomicAdd(out_ent + (size_t)h * CH + c, v);
    if (c == 0) unsafeAtomicAdd(counts + h, 1.0f);
}

__global__ void user_agg_atomic_kernel(const float* __restrict__ emb,
                                       const float* __restrict__ region_ent,
                                       const int* __restrict__ irows,
                                       const int* __restrict__ icols,
                                       const float* __restrict__ ivals,
                                       float* __restrict__ out_user, int NNZ) {
    const long long gid = (long long)blockIdx.x * blockDim.x + threadIdx.x;
    const long long i = gid >> 6;
    if (i >= NNZ) return;
    const int c = (int)gid & 63;
    const float v = ivals[i] * ent_val(emb, region_ent, icols[i], c);
    unsafeAtomicAdd(out_user + (size_t)irows[i] * CH + c, v);
}

__global__ void finalize_kernel(float* __restrict__ out_ent,
                                const float* __restrict__ counts, int n_entities) {
    const int gid = blockIdx.x * blockDim.x + threadIdx.x;
    if (gid >= n_entities * CH) return;
    out_ent[gid] /= fmaxf(counts[gid >> 6], 1.0f);
}

// =========================================================================
extern "C" void kernel_launch(void* const* d_in, const int* in_sizes, int n_in,
                              void* d_out, int out_size, void* d_ws, size_t ws_size,
                              hipStream_t stream) {
    const float* entity_emb = (const float*)d_in[0];
    const int*   edge_index = (const int*)d_in[2];
    const int*   edge_type  = (const int*)d_in[3];
    const int*   irows      = (const int*)d_in[4];
    const int*   icols      = (const int*)d_in[5];
    const float* ivals      = (const float*)d_in[6];
    const float* Wreg       = (const float*)d_in[7];
    const float* weight     = (const float*)d_in[8];

    const int n_entities = in_sizes[0] / CH;
    const int n_users    = in_sizes[1] / CH;
    const int E          = in_sizes[3];
    const int NNZ        = in_sizes[4];
    const int n_rel      = in_sizes[8] / CH;

    float* out_ent  = (float*)d_out;
    float* out_user = out_ent + (size_t)n_entities * CH;

    const int NBUK_E = (n_entities + 63) >> 6;
    const int NBUK_U = (n_users + 63) >> 6;
    const int n_e = NBUK_E * NB;
    const int n_u = NBUK_U * NB;
    const int nbse = (n_e + SCAN_B - 1) / SCAN_B;
    const int nbsu = (n_u + SCAN_B - 1) / SCAN_B;

    // ---- tier-1 (bucket) layout ----
    char* w = (char*)d_ws;
    auto take = [&](size_t bytes) {
        char* p = w;
        w += (bytes + 7) & ~(size_t)7;
        return p;
    };
    float*    region_ent = (float*)take((size_t)RN * CH * 4);
    ushort_t* e_t        = (ushort_t*)take((size_t)CH * KP * 2);
    ushort_t* ebf        = (ushort_t*)take((size_t)n_entities * CH * 2);
    int*      sorted_tr  = (int*)take((size_t)E * 4);
    uint2*    upack      = (uint2*)take((size_t)NNZ * 8);
    int*      offs_e     = (int*)take((size_t)(n_entities + 1) * 4);
    int*      offs_u     = (int*)take((size_t)(n_users + 1) * 4);
    int*      bsums      = (int*)take(512 * 4);
    int*      hist_e     = (int*)take((size_t)n_e * 4);
    int*      exbase_e   = (int*)take((size_t)(n_e + 1) * 4);
    int*      hist_u     = (int*)take((size_t)n_u * 4);
    int*      exbase_u   = (int*)take((size_t)(n_u + 1) * 4);
    int*      pcode_e    = (int*)take((size_t)E * 4);
    uint2*    pcode_u    = (uint2*)take((size_t)NNZ * 8);
    const size_t need_bucket = (size_t)(w - (char*)d_ws);

    const bool common_ok = (n_entities < (1 << 17)) && (n_rel <= 32);
    const bool use_bucket = common_ok && (ws_size >= need_bucket) &&
                            (NBUK_E <= MAXBUK) && (NBUK_U <= MAXBUK) &&
                            (nbse <= 512) && (nbsu <= 512);

    // ---- tier-2 (csr) layout ----
    char* w2 = (char*)d_ws;
    auto take2 = [&](size_t bytes) {
        char* p = w2;
        w2 += (bytes + 7) & ~(size_t)7;
        return p;
    };
    float*    c_region  = (float*)take2((size_t)RN * CH * 4);
    int*      c_offs_e  = (int*)take2((size_t)(n_entities + 1) * 4);
    int*      c_cur_e   = (int*)take2((size_t)n_entities * 4);
    int*      c_offs_u  = (int*)take2((size_t)(n_users + 1) * 4);
    int*      c_cur_u   = (int*)take2((size_t)n_users * 4);
    int*      c_bsums   = (int*)take2(512 * 4);
    int*      c_sorted  = (int*)take2((size_t)E * 4);
    uint2*    c_upack   = (uint2*)take2((size_t)NNZ * 8);
    ushort_t* c_et      = (ushort_t*)take2((size_t)CH * KP * 2);
    ushort_t* c_ebf     = (ushort_t*)take2((size_t)n_entities * CH * 2);
    const size_t need_csr = (size_t)(w2 - (char*)d_ws);
    const int nb_e = (n_entities + SCAN_B - 1) / SCAN_B;
    const int nb_u = (n_users + SCAN_B - 1) / SCAN_B;
    const bool use_csr = common_ok && (ws_size >= need_csr) &&
                         (nb_e <= 512) && (nb_u <= 512);

    if (use_bucket) {
        region_init_kernel<<<(RN * CH / 4 + 255) / 256, 256, 0, stream>>>(entity_emb, region_ent);
        {
            const int tot = CH * (KP / 8);
            build_et_kernel<<<(tot + 255) / 256, 256, 0, stream>>>(entity_emb, e_t);
        }
        region_gemm_mfma_kernel<<<MT_BLKS * KCHUNKS, 256, 0, stream>>>(
            Wreg, e_t, region_ent);
        {
            const int tot = n_entities * (CH / 8);
            build_ebf_kernel<<<(tot + 255) / 256, 256, 0, stream>>>(
                entity_emb, region_ent, ebf, n_entities);
        }

        bucket_hist2_kernel<<<2 * NB, T1, 0, stream>>>(
            edge_index, E, NBUK_E, irows, NNZ, NBUK_U, hist_e, hist_u);

        scan_block_kernel<<<nbse, SCAN_B, 0, stream>>>(hist_e, exbase_e, bsums, n_e);
        scan_top_kernel<<<1, 512, 0, stream>>>(bsums, nbse);
        scan_add_kernel<<<nbse, SCAN_B, 0, stream>>>(exbase_e, bsums, n_e);

        scan_block_kernel<<<nbsu, SCAN_B, 0, stream>>>(hist_u, exbase_u, bsums, n_u);
        scan_top_kernel<<<1, 512, 0, stream>>>(bsums, nbsu);
        scan_add_kernel<<<nbsu, SCAN_B, 0, stream>>>(exbase_u, bsums, n_u);

        pass2_combined_kernel<<<2 * NB, T1, 0, stream>>>(
            edge_index, edge_type, exbase_e, pcode_e, E, n_rel, NBUK_E,
            irows, icols, ivals, exbase_u, pcode_u, NNZ, NBUK_U);

        bucket_sort2_kernel<<<NBUK_E + NBUK_U, 256, 0, stream>>>(
            pcode_e, exbase_e, sorted_tr, offs_e, n_entities, NBUK_E,
            pcode_u, exbase_u, upack, offs_u, n_users, NBUK_U);

        kg_gather_bf_kernel<<<(n_entities + 3) / 4, 256, n_rel * WSTR * 4, stream>>>(
            ebf, sorted_tr, offs_e, weight, out_ent, n_entities, n_rel);
        user_gather_bf_kernel<<<(n_users + 3) / 4, 256, 0, stream>>>(
            ebf, upack, offs_u, out_user, n_users);
    } else if (use_csr) {
        const unsigned smul_e = (unsigned)((8ULL << 32) / (unsigned long long)n_entities);
        const unsigned smul_u = (unsigned)((8ULL << 32) / (unsigned long long)n_users);

        region_init_kernel<<<(RN * CH / 4 + 255) / 256, 256, 0, stream>>>(entity_emb, c_region);
        {
            const int tot = CH * (KP / 8);
            build_et_kernel<<<(tot + 255) / 256, 256, 0, stream>>>(entity_emb, c_et);
        }
        region_gemm_mfma_kernel<<<MT_BLKS * KCHUNKS, 256, 0, stream>>>(
            Wreg, c_et, c_region);
        {
            const int tot = n_entities * (CH / 8);
            build_ebf_kernel<<<(tot + 255) / 256, 256, 0, stream>>>(
                entity_emb, c_region, c_ebf, n_entities);
        }

        hipMemsetAsync(c_cur_e, 0, (size_t)n_entities * 4, stream);
        hipMemsetAsync(c_cur_u, 0, (size_t)n_users * 4, stream);
        hist_sliced_kernel<<<NSLICE * SLICE_RB, 256, 0, stream>>>(
            edge_index, c_cur_e, E, smul_e);
        hist_sliced_kernel<<<NSLICE * SLICE_RB, 256, 0, stream>>>(
            irows, c_cur_u, NNZ, smul_u);

        scan_block_kernel<<<nb_e, SCAN_B, 0, stream>>>(c_cur_e, c_offs_e, c_bsums, n_entities);
        scan_top_kernel<<<1, 512, 0, stream>>>(c_bsums, nb_e);
        scan_add_kernel<<<nb_e, SCAN_B, 0, stream>>>(c_offs_e, c_bsums, n_entities);

        scan_block_kernel<<<nb_u, SCAN_B, 0, stream>>>(c_cur_u, c_offs_u, c_bsums, n_users);
        scan_top_kernel<<<1, 512, 0, stream>>>(c_bsums, nb_u);
        scan_add_kernel<<<nb_u, SCAN_B, 0, stream>>>(c_offs_u, c_bsums, n_users);

        hipMemsetAsync(c_cur_e, 0, (size_t)n_entities * 4, stream);
        hipMemsetAsync(c_cur_u, 0, (size_t)n_users * 4, stream);
        scatter_e_sliced_kernel<<<NSLICE * SLICE_RB, 256, 0, stream>>>(
            edge_index, edge_type, c_offs_e, c_cur_e, c_sorted, E, n_rel, smul_e);
        scatter_u_sliced_kernel<<<NSLICE * SLICE_RB, 256, 0, stream>>>(
            irows, icols, ivals, c_offs_u, c_cur_u, c_upack, NNZ, smul_u);

        kg_gather_bf_kernel<<<(n_entities + 3) / 4, 256, n_rel * WSTR * 4, stream>>>(
            c_ebf, c_sorted, c_offs_e, weight, out_ent, n_entities, n_rel);
        user_gather_bf_kernel<<<(n_users + 3) / 4, 256, 0, stream>>>(
            c_ebf, c_upack, c_offs_u, out_user, n_users);
    } else {
        // tier-3: atomic fallback
        float* region3 = (float*)d_ws;
        float* counts  = region3 + (size_t)RN * CH;
        region_init_kernel<<<(RN * CH / 4 + 255) / 256, 256, 0, stream>>>(entity_emb, region3);
        region_gemm_kernel<<<ROW_TILES * KSPLIT, 256, 0, stream>>>(
            entity_emb, Wreg, region3);
        hipMemsetAsync(d_out, 0, (size_t)out_size * sizeof(float), stream);
        hipMemsetAsync(counts, 0, (size_t)n_entities * sizeof(float), stream);
        {
            const long long tot = (long long)E * CH;
            kg_agg_atomic_kernel<<<(int)((tot + 255) / 256), 256, 0, stream>>>(
                entity_emb, region3, edge_index, edge_type, weight,
                out_ent, counts, E, n_rel);
        }
        {
            const long long tot = (long long)NNZ * CH;
            user_agg_atomic_kernel<<<(int)((tot + 255) / 256), 256, 0, stream>>>(
                entity_emb, region3, irows, icols, ivals, out_user, NNZ);
        }
        finalize_kernel<<<(n_entities * CH + 255) / 256, 256, 0, stream>>>(
            out_ent, counts, n_entities);
    }
}

// Round 26
// 180.412 us; speedup vs baseline: 1.0870x; 1.0870x over previous
//
#include <hip/hip_runtime.h>
#include <hip/hip_bf16.h>

// Problem constants (from reference source)
#define REGION_R0 42033
#define REGION_R1 44630
#define RN        (REGION_R1 - REGION_R0)   // 2597
#define CH        64
#define KSPLIT    32
#define ROW_TILES ((RN + 31) / 32)          // 82
#define SCAN_B    256
#define NSLICE    8
#define SLICE_RB  256                        // tier-2 grid

// bucket partition geometry
#define NB        64                         // range-blocks: 16-entry (64B) exclusive runs
#define T1        1024                       // 16 waves/block
#define MAXBUK    2048

// MFMA region-gemm geometry
#define KTT       82
#define KP        (KTT * 32)                 // 2624
#define PERCHUNK  6
#define KCHUNKS   14
#define MT_TILES  163
#define MT_BLKS   41

typedef unsigned short ushort_t;
typedef short  bfrag8 __attribute__((ext_vector_type(8)));
typedef float  f32x4v __attribute__((ext_vector_type(4)));

__device__ __forceinline__ unsigned pack2bf(float a, float b) {
    unsigned ua = __float_as_uint(a);
    unsigned ub = __float_as_uint(b);
    ua += 0x7fffu + ((ua >> 16) & 1u);   // RNE
    ub += 0x7fffu + ((ub >> 16) & 1u);
    return ((ua >> 16) & 0xffffu) | (ub & 0xffff0000u);
}

__device__ __forceinline__ float bf_lo(unsigned u) { return __uint_as_float(u << 16); }
__device__ __forceinline__ float bf_hi(unsigned u) { return __uint_as_float(u & 0xffff0000u); }

// =========================================================================
// Fused region init + e_t build (independent, one launch).
// blocks [0,IB): region_ent = 0.8*emb[R0:R1];  [IB,IB+EB): e_t transpose.
// =========================================================================
#define IB_INIT   ((RN * CH / 4 + 255) / 256)     // 163
#define EB_ET     ((CH * (KP / 8) + 255) / 256)   // 82

__global__ void region_init_et_kernel(const float* __restrict__ emb,
                                      float* __restrict__ region_ent,
                                      ushort_t* __restrict__ e_t) {
    if ((int)blockIdx.x < IB_INIT) {
        const int gid = blockIdx.x * 256 + threadIdx.x;
        if (gid >= RN * CH / 4) return;
        const float4 v = reinterpret_cast<const float4*>(emb + (size_t)REGION_R0 * CH)[gid];
        float4 o;
        o.x = 0.8f * v.x; o.y = 0.8f * v.y; o.z = 0.8f * v.z; o.w = 0.8f * v.w;
        reinterpret_cast<float4*>(region_ent)[gid] = o;
    } else {
        const int gid = (blockIdx.x - IB_INIT) * 256 + threadIdx.x;
        if (gid >= CH * (KP / 8)) return;
        const int c  = gid / (KP / 8);
        const int k8 = gid - c * (KP / 8);
        const int kb = k8 * 8;
        float v[8];
#pragma unroll
        for (int j = 0; j < 8; ++j) {
            const int k = kb + j;
            v[j] = (k < RN) ? emb[(size_t)(REGION_R0 + k) * CH + c] : 0.0f;
        }
        uint4 o;
        o.x = pack2bf(v[0], v[1]); o.y = pack2bf(v[2], v[3]);
        o.z = pack2bf(v[4], v[5]); o.w = pack2bf(v[6], v[7]);
        *reinterpret_cast<uint4*>(e_t + (size_t)c * KP + kb) = o;
    }
}

// =========================================================================
// MFMA region GEMM (R14-verified, absmax 0.25)
// =========================================================================
__global__ void region_gemm_mfma_kernel(const float* __restrict__ W,
                                        const ushort_t* __restrict__ e_t,
                                        float* __restrict__ region_ent) {
    const int wv    = threadIdx.x >> 6;
    const int lane  = threadIdx.x & 63;
    const int blk_m = blockIdx.x / KCHUNKS;
    const int kc    = blockIdx.x - blk_m * KCHUNKS;
    const int mt    = blk_m * 4 + wv;
    if (mt >= MT_TILES) return;
    const int l15 = lane & 15;
    const int lg  = lane >> 4;

    int arow = mt * 16 + l15;
    if (arow >= RN) arow = RN - 1;
    const float* wrow = W + (size_t)arow * RN;

    const int kt0 = kc * PERCHUNK;
    const int kt1 = (kt0 + PERCHUNK < KTT) ? (kt0 + PERCHUNK) : KTT;

    f32x4v acc[4];
#pragma unroll
    for (int n = 0; n < 4; ++n) acc[n] = (f32x4v){0.f, 0.f, 0.f, 0.f};

    for (int kt = kt0; kt < kt1; ++kt) {
        const int kb = kt * 32 + lg * 8;
        union { uint4 u; bfrag8 f; } A;
        if (kb + 8 <= RN) {
            float v0 = wrow[kb + 0], v1 = wrow[kb + 1];
            float v2 = wrow[kb + 2], v3 = wrow[kb + 3];
            float v4 = wrow[kb + 4], v5 = wrow[kb + 5];
            float v6 = wrow[kb + 6], v7 = wrow[kb + 7];
            A.u.x = pack2bf(v0, v1); A.u.y = pack2bf(v2, v3);
            A.u.z = pack2bf(v4, v5); A.u.w = pack2bf(v6, v7);
        } else {
            float v[8];
#pragma unroll
            for (int j = 0; j < 8; ++j) {
                const int k = kb + j;
                v[j] = (k < RN) ? wrow[k] : 0.0f;
            }
            A.u.x = pack2bf(v[0], v[1]); A.u.y = pack2bf(v[2], v[3]);
            A.u.z = pack2bf(v[4], v[5]); A.u.w = pack2bf(v[6], v[7]);
        }
#pragma unroll
        for (int n = 0; n < 4; ++n) {
            const bfrag8 B = *reinterpret_cast<const bfrag8*>(
                e_t + (size_t)(n * 16 + l15) * KP + kb);
            acc[n] = __builtin_amdgcn_mfma_f32_16x16x32_bf16(A.f, B, acc[n], 0, 0, 0);
        }
    }

#pragma unroll
    for (int n = 0; n < 4; ++n) {
#pragma unroll
        for (int j = 0; j < 4; ++j) {
            const int row = mt * 16 + lg * 4 + j;
            if (row < RN)
                unsafeAtomicAdd(region_ent + (size_t)row * CH + n * 16 + l15,
                                0.2f * acc[n][j]);
        }
    }
}

// =========================================================================
// VALU region GEMM (tier-3 fallback only)
// =========================================================================
__global__ void region_init_kernel(const float* __restrict__ emb,
                                   float* __restrict__ region_ent) {
    const int gid = blockIdx.x * blockDim.x + threadIdx.x;
    if (gid >= RN * CH / 4) return;
    const float4 v = reinterpret_cast<const float4*>(emb + (size_t)REGION_R0 * CH)[gid];
    float4 o;
    o.x = 0.8f * v.x; o.y = 0.8f * v.y; o.z = 0.8f * v.z; o.w = 0.8f * v.w;
    reinterpret_cast<float4*>(region_ent)[gid] = o;
}

__global__ void region_gemm_kernel(const float* __restrict__ emb,
                                   const float* __restrict__ W,
                                   float* __restrict__ region_ent) {
    const int wave = threadIdx.x >> 6;
    const int c    = threadIdx.x & 63;
    const int rt   = blockIdx.x / KSPLIT;
    const int ks   = blockIdx.x - rt * KSPLIT;
    const int base = rt * 32 + wave * 8;
    if (base >= RN) return;

    const int k0 = (RN * ks) / KSPLIT;
    const int k1 = (RN * (ks + 1)) / KSPLIT;

    const float* wp[8];
#pragma unroll
    for (int r = 0; r < 8; ++r) {
        int row = base + r;
        if (row >= RN) row = RN - 1;
        row = __builtin_amdgcn_readfirstlane(row);
        wp[r] = W + (size_t)row * RN;
    }
    const float* ep = emb + (size_t)REGION_R0 * CH + c;

    float acc[8];
#pragma unroll
    for (int r = 0; r < 8; ++r) acc[r] = 0.0f;

    int k = k0;
    for (; k + 4 <= k1; k += 4) {
        const float e0 = ep[(size_t)(k + 0) * CH];
        const float e1 = ep[(size_t)(k + 1) * CH];
        const float e2 = ep[(size_t)(k + 2) * CH];
        const float e3 = ep[(size_t)(k + 3) * CH];
#pragma unroll
        for (int r = 0; r < 8; ++r) {
            const float* wr = wp[r];
            float a = acc[r];
            a = fmaf(wr[k + 0], e0, a);
            a = fmaf(wr[k + 1], e1, a);
            a = fmaf(wr[k + 2], e2, a);
            a = fmaf(wr[k + 3], e3, a);
            acc[r] = a;
        }
    }
    for (; k < k1; ++k) {
        const float e = ep[(size_t)k * CH];
#pragma unroll
        for (int r = 0; r < 8; ++r) acc[r] = fmaf(wp[r][k], e, acc[r]);
    }
#pragma unroll
    for (int r = 0; r < 8; ++r) {
        const int row = base + r;
        if (row < RN)
            unsafeAtomicAdd(region_ent + (size_t)row * CH + c, 0.2f * acc[r]);
    }
}

__device__ __forceinline__ float ent_val(const float* __restrict__ emb,
                                         const float* __restrict__ region_ent,
                                         int row, int c) {
    const float* p = (row >= REGION_R0 && row < REGION_R1)
                         ? (region_ent + (size_t)(row - REGION_R0) * CH + c)
                         : (emb + (size_t)row * CH + c);
    return *p;
}

__device__ __forceinline__ const float* ent_row(const float* __restrict__ emb,
                                                const float* __restrict__ region_ent,
                                                int row) {
    return (row >= REGION_R0 && row < REGION_R1)
               ? (region_ent + (size_t)(row - REGION_R0) * CH)
               : (emb + (size_t)row * CH);
}

// =========================================================================
// bf16 entity table (region rows baked in)
// =========================================================================
__global__ void build_ebf_kernel(const float* __restrict__ emb,
                                 const float* __restrict__ region_ent,
                                 ushort_t* __restrict__ ebf,
                                 int n_entities) {
    const int gid = blockIdx.x * blockDim.x + threadIdx.x;
    if (gid >= n_entities * (CH / 8)) return;
    const int row = gid >> 3;
    const int co  = (gid & 7) * 8;
    const float* rp = ent_row(emb, region_ent, row) + co;
    const float4 a = *reinterpret_cast<const float4*>(rp);
    const float4 b = *reinterpret_cast<const float4*>(rp + 4);
    uint4 o;
    o.x = pack2bf(a.x, a.y);
    o.y = pack2bf(a.z, a.w);
    o.z = pack2bf(b.x, b.y);
    o.w = pack2bf(b.z, b.w);
    *reinterpret_cast<uint4*>(ebf + (size_t)row * CH + co) = o;
}

// =========================================================================
// Combined bucket hist (R23-proven: x4 unrolled key loads)
// =========================================================================
__global__ void bucket_hist2_kernel(const int* __restrict__ ekeys, int ne, int nbe,
                                    const int* __restrict__ ukeys, int nu, int nbu,
                                    int* __restrict__ hist_e,
                                    int* __restrict__ hist_u) {
    __shared__ int lh[MAXBUK];
    const bool is_u = (blockIdx.x >= NB);
    const int  rb   = is_u ? (blockIdx.x - NB) : blockIdx.x;
    const int* keys = is_u ? ukeys : ekeys;
    const int  n    = is_u ? nu : ne;
    const int  nbuk = is_u ? nbu : nbe;
    int* hist       = is_u ? hist_u : hist_e;

    for (int i = threadIdx.x; i < nbuk; i += T1) lh[i] = 0;
    __syncthreads();
    const int chunk = (n + NB - 1) / NB;
    const int i0 = rb * chunk;
    const int i1 = min(i0 + chunk, n);
    int i = i0 + (int)threadIdx.x;
    for (; i + 3 * T1 < i1; i += 4 * T1) {
        const int k0 = keys[i];
        const int k1 = keys[i + T1];
        const int k2 = keys[i + 2 * T1];
        const int k3 = keys[i + 3 * T1];
        atomicAdd(&lh[k0 >> 6], 1);
        atomicAdd(&lh[k1 >> 6], 1);
        atomicAdd(&lh[k2 >> 6], 1);
        atomicAdd(&lh[k3 >> 6], 1);
    }
    for (; i < i1; i += T1)
        atomicAdd(&lh[keys[i] >> 6], 1);
    __syncthreads();
    for (int b = threadIdx.x; b < nbuk; b += T1)
        hist[(size_t)b * NB + rb] = lh[b];
}

// =========================================================================
// Fused two-array scans (tier-1): blocks [0,nbse) = edges, rest = users
// =========================================================================
__global__ void scan_block2_kernel(const int* __restrict__ ce, int* __restrict__ oe,
                                   int* __restrict__ bse, int ne2, int nbse,
                                   const int* __restrict__ cu, int* __restrict__ ou,
                                   int* __restrict__ bsu, int nu2) {
    __shared__ int s[SCAN_B];
    const bool is_u = ((int)blockIdx.x >= nbse);
    const int  rb   = is_u ? (blockIdx.x - nbse) : blockIdx.x;
    const int* counts = is_u ? cu : ce;
    int* offs  = is_u ? ou : oe;
    int* bsums = is_u ? bsu : bse;
    const int n = is_u ? nu2 : ne2;

    const int i = rb * SCAN_B + threadIdx.x;
    s[threadIdx.x] = (i < n) ? counts[i] : 0;
    __syncthreads();
    for (int d = 1; d < SCAN_B; d <<= 1) {
        const int t = (threadIdx.x >= d) ? s[threadIdx.x - d] : 0;
        __syncthreads();
        s[threadIdx.x] += t;
        __syncthreads();
    }
    if (i < n) offs[i + 1] = s[threadIdx.x];
    if (threadIdx.x == SCAN_B - 1) bsums[rb] = s[threadIdx.x];
    if (rb == 0 && threadIdx.x == 0) offs[0] = 0;
}

__global__ void scan_top2_kernel(int* __restrict__ bse, int nbe2,
                                 int* __restrict__ bsu, int nbu2) {
    __shared__ int s[512];
    int* bsums = blockIdx.x ? bsu : bse;
    const int nb = blockIdx.x ? nbu2 : nbe2;
    s[threadIdx.x] = (threadIdx.x < (unsigned)nb) ? bsums[threadIdx.x] : 0;
    __syncthreads();
    for (int d = 1; d < 512; d <<= 1) {
        const int t = (threadIdx.x >= d) ? s[threadIdx.x - d] : 0;
        __syncthreads();
        s[threadIdx.x] += t;
        __syncthreads();
    }
    if (threadIdx.x < (unsigned)nb) bsums[threadIdx.x] = s[threadIdx.x];
}

__global__ void scan_add2_kernel(int* __restrict__ oe, const int* __restrict__ bse,
                                 int ne2, int nbse,
                                 int* __restrict__ ou, const int* __restrict__ bsu,
                                 int nu2) {
    const bool is_u = ((int)blockIdx.x >= nbse);
    const int  rb   = is_u ? (blockIdx.x - nbse) : blockIdx.x;
    if (rb == 0) return;
    int* offs = is_u ? ou : oe;
    const int* bsums = is_u ? bsu : bse;
    const int n = is_u ? nu2 : ne2;
    const int i = rb * SCAN_B + threadIdx.x;
    if (i < n) offs[i + 1] += bsums[rb - 1];
}

// tier-2 single-array scans
__global__ void scan_block_kernel(const int* __restrict__ counts, int* __restrict__ offs,
                                  int* __restrict__ bsums, int n) {
    __shared__ int s[SCAN_B];
    const int i = blockIdx.x * SCAN_B + threadIdx.x;
    s[threadIdx.x] = (i < n) ? counts[i] : 0;
    __syncthreads();
    for (int d = 1; d < SCAN_B; d <<= 1) {
        const int t = (threadIdx.x >= d) ? s[threadIdx.x - d] : 0;
        __syncthreads();
        s[threadIdx.x] += t;
        __syncthreads();
    }
    if (i < n) offs[i + 1] = s[threadIdx.x];
    if (threadIdx.x == SCAN_B - 1) bsums[blockIdx.x] = s[threadIdx.x];
    if (blockIdx.x == 0 && threadIdx.x == 0) offs[0] = 0;
}

__global__ void scan_top_kernel(int* __restrict__ bsums, int nb) {
    __shared__ int s[512];
    s[threadIdx.x] = (threadIdx.x < (unsigned)nb) ? bsums[threadIdx.x] : 0;
    __syncthreads();
    for (int d = 1; d < 512; d <<= 1) {
        const int t = (threadIdx.x >= d) ? s[threadIdx.x - d] : 0;
        __syncthreads();
        s[threadIdx.x] += t;
        __syncthreads();
    }
    if (threadIdx.x < (unsigned)nb) bsums[threadIdx.x] = s[threadIdx.x];
}

__global__ void scan_add_kernel(int* __restrict__ offs, const int* __restrict__ bsums, int n) {
    if (blockIdx.x == 0) return;
    const int i = blockIdx.x * SCAN_B + threadIdx.x;
    if (i < n) offs[i + 1] += bsums[blockIdx.x - 1];
}

// =========================================================================
// Combined pass2 (R23-proven: x4 unrolled chains)
// =========================================================================
__global__ void pass2_combined_kernel(const int* __restrict__ edge_index,
                                      const int* __restrict__ edge_type,
                                      const int* __restrict__ exbase_e,
                                      int* __restrict__ pcode_e,
                                      int E, int n_rel, int nbe,
                                      const int* __restrict__ irows,
                                      const int* __restrict__ icols,
                                      const float* __restrict__ ivals,
                                      const int* __restrict__ exbase_u,
                                      uint2* __restrict__ pcode_u,
                                      int NNZ, int nbu) {
    __shared__ int cur[MAXBUK];
    __shared__ int exb[MAXBUK];
    const bool is_u = (blockIdx.x >= NB);
    const int  rb   = is_u ? (blockIdx.x - NB) : blockIdx.x;
    const int  nbuk = is_u ? nbu : nbe;
    const int* exbase = is_u ? exbase_u : exbase_e;

    for (int i = threadIdx.x; i < nbuk; i += T1) {
        cur[i] = 0;
        exb[i] = exbase[(size_t)i * NB + rb];
    }
    __syncthreads();

    if (!is_u) {
        const int chunk = (E + NB - 1) / NB;
        const int i0 = rb * chunk;
        const int i1 = min(i0 + chunk, E);
        int e = i0 + (int)threadIdx.x;
        for (; e + 3 * T1 < i1; e += 4 * T1) {
            const int h0 = edge_index[e];
            const int h1 = edge_index[e + T1];
            const int h2 = edge_index[e + 2 * T1];
            const int h3 = edge_index[e + 3 * T1];
            const int t0 = edge_index[(size_t)E + e];
            const int t1 = edge_index[(size_t)E + e + T1];
            const int t2 = edge_index[(size_t)E + e + 2 * T1];
            const int t3 = edge_index[(size_t)E + e + 3 * T1];
            int r0 = edge_type[e] - 1;             if (r0 < 0) r0 += n_rel;
            int r1 = edge_type[e + T1] - 1;        if (r1 < 0) r1 += n_rel;
            int r2 = edge_type[e + 2 * T1] - 1;    if (r2 < 0) r2 += n_rel;
            int r3 = edge_type[e + 3 * T1] - 1;    if (r3 < 0) r3 += n_rel;
            const int b0 = h0 >> 6, b1 = h1 >> 6, b2 = h2 >> 6, b3 = h3 >> 6;
            const int l0 = atomicAdd(&cur[b0], 1);
            const int l1 = atomicAdd(&cur[b1], 1);
            const int l2 = atomicAdd(&cur[b2], 1);
            const int l3 = atomicAdd(&cur[b3], 1);
            pcode_e[exb[b0] + l0] = ((h0 & 63) << 22) | (r0 << 17) | t0;
            pcode_e[exb[b1] + l1] = ((h1 & 63) << 22) | (r1 << 17) | t1;
            pcode_e[exb[b2] + l2] = ((h2 & 63) << 22) | (r2 << 17) | t2;
            pcode_e[exb[b3] + l3] = ((h3 & 63) << 22) | (r3 << 17) | t3;
        }
        for (; e < i1; e += T1) {
            const int h = edge_index[e];
            const int b = h >> 6;
            const int loc = atomicAdd(&cur[b], 1);
            const int pos = exb[b] + loc;
            const int t = edge_index[(size_t)E + e];
            int r = edge_type[e] - 1;
            if (r < 0) r += n_rel;
            pcode_e[pos] = ((h & 63) << 22) | (r << 17) | t;
        }
    } else {
        const int chunk = (NNZ + NB - 1) / NB;
        const int i0 = rb * chunk;
        const int i1 = min(i0 + chunk, NNZ);
        int i = i0 + (int)threadIdx.x;
        for (; i + 3 * T1 < i1; i += 4 * T1) {
            const int u0 = irows[i];
            const int u1 = irows[i + T1];
            const int u2 = irows[i + 2 * T1];
            const int u3 = irows[i + 3 * T1];
            const int c0 = icols[i];
            const int c1 = icols[i + T1];
            const int c2 = icols[i + 2 * T1];
            const int c3 = icols[i + 3 * T1];
            const float v0 = ivals[i];
            const float v1 = ivals[i + T1];
            const float v2 = ivals[i + 2 * T1];
            const float v3 = ivals[i + 3 * T1];
            const int b0 = u0 >> 6, b1 = u1 >> 6, b2 = u2 >> 6, b3 = u3 >> 6;
            const int l0 = atomicAdd(&cur[b0], 1);
            const int l1 = atomicAdd(&cur[b1], 1);
            const int l2 = atomicAdd(&cur[b2], 1);
            const int l3 = atomicAdd(&cur[b3], 1);
            uint2 cv;
            cv.x = ((unsigned)(u0 & 63) << 17) | (unsigned)c0;
            cv.y = __float_as_uint(v0);
            pcode_u[exb[b0] + l0] = cv;
            cv.x = ((unsigned)(u1 & 63) << 17) | (unsigned)c1;
            cv.y = __float_as_uint(v1);
            pcode_u[exb[b1] + l1] = cv;
            cv.x = ((unsigned)(u2 & 63) << 17) | (unsigned)c2;
            cv.y = __float_as_uint(v2);
            pcode_u[exb[b2] + l2] = cv;
            cv.x = ((unsigned)(u3 & 63) << 17) | (unsigned)c3;
            cv.y = __float_as_uint(v3);
            pcode_u[exb[b3] + l3] = cv;
        }
        for (; i < i1; i += T1) {
            const int u = irows[i];
            const int b = u >> 6;
            const int loc = atomicAdd(&cur[b], 1);
            const int pos = exb[b] + loc;
            uint2 cv;
            cv.x = ((unsigned)(u & 63) << 17) | (unsigned)icols[i];
            cv.y = __float_as_uint(ivals[i]);
            pcode_u[pos] = cv;
        }
    }
}

// =========================================================================
// Combined per-bucket counting sort (R20-proven)
// =========================================================================
__global__ void bucket_sort2_kernel(const int* __restrict__ pcode_e,
                                    const int* __restrict__ exbase_e,
                                    int* __restrict__ sorted_tr,
                                    int* __restrict__ offs_e,
                                    int n_entities, int nbe,
                                    const uint2* __restrict__ pcode_u,
                                    const int* __restrict__ exbase_u,
                                    uint2* __restrict__ upack,
                                    int* __restrict__ offs_u,
                                    int n_users, int nbu) {
    __shared__ int cnt[64];
    __shared__ int off[64];
    __shared__ int cur[64];
    const bool is_u = (blockIdx.x >= (unsigned)nbe);
    const int  b    = is_u ? (blockIdx.x - nbe) : blockIdx.x;
    const int* exbase = is_u ? exbase_u : exbase_e;
    const int bstart = exbase[(size_t)b * NB];
    const int bend   = exbase[(size_t)(b + 1) * NB];
    if (threadIdx.x < 64) { cnt[threadIdx.x] = 0; cur[threadIdx.x] = 0; }
    __syncthreads();

    if (!is_u) {
        for (int i = bstart + (int)threadIdx.x; i < bend; i += blockDim.x)
            atomicAdd(&cnt[(pcode_e[i] >> 22) & 63], 1);
    } else {
        for (int i = bstart + (int)threadIdx.x; i < bend; i += blockDim.x)
            atomicAdd(&cnt[(pcode_u[i].x >> 17) & 63], 1);
    }
    __syncthreads();
    if (threadIdx.x == 0) {
        int s = 0;
#pragma unroll
        for (int i = 0; i < 64; ++i) { off[i] = s; s += cnt[i]; }
    }
    __syncthreads();

    if (!is_u) {
        const int h0 = b * 64;
        if (threadIdx.x < 64) {
            const int h = h0 + (int)threadIdx.x;
            if (h < n_entities) offs_e[h] = bstart + off[threadIdx.x];
        }
        if (b == nbe - 1 && threadIdx.x == 0) offs_e[n_entities] = bend;
        for (int i = bstart + (int)threadIdx.x; i < bend; i += blockDim.x) {
            const int p  = pcode_e[i];
            const int lh = (p >> 22) & 63;
            const int pos = bstart + off[lh] + atomicAdd(&cur[lh], 1);
            sorted_tr[pos] = p & 0x3FFFFF;
        }
    } else {
        const int u0 = b * 64;
        if (threadIdx.x < 64) {
            const int u = u0 + (int)threadIdx.x;
            if (u < n_users) offs_u[u] = bstart + off[threadIdx.x];
        }
        if (b == nbu - 1 && threadIdx.x == 0) offs_u[n_users] = bend;
        for (int i = bstart + (int)threadIdx.x; i < bend; i += blockDim.x) {
            const uint2 cv = pcode_u[i];
            const int lr = (int)(cv.x >> 17) & 63;
            const int pos = bstart + off[lr] + atomicAdd(&cur[lr], 1);
            uint2 o;
            o.x = cv.x & 0x1FFFFu;
            o.y = cv.y;
            upack[pos] = o;
        }
    }
}

// =========================================================================
// Fused bf16 gathers (R25): blocks [0,nwe) = entities, rest = users.
// v3 layout: 8 lanes/row x uint4, x2 unroll. Weight LDS unpadded (R23).
// =========================================================================
__global__ void gather2_kernel(const ushort_t* __restrict__ ebf,
                               const int* __restrict__ sorted_tr,
                               const int* __restrict__ offs_e,
                               const float* __restrict__ weight,
                               float* __restrict__ out_ent,
                               int n_entities, int n_rel, int nwe,
                               const uint2* __restrict__ upack,
                               const int* __restrict__ offs_u,
                               float* __restrict__ out_user,
                               int n_users) {
    extern __shared__ float wl[];   // n_rel * CH (entity blocks only)
    const int lane = threadIdx.x & 63;
    const int g    = lane >> 3;     // edge slot 0..7
    const int q8   = lane & 7;      // channel octet 0..7

    if ((int)blockIdx.x < nwe) {
        for (int i = threadIdx.x; i < n_rel * CH; i += blockDim.x) wl[i] = weight[i];
        __syncthreads();
        const float4* wl4 = reinterpret_cast<const float4*>(wl);

        const int wid = (blockIdx.x * blockDim.x + threadIdx.x) >> 6;
        if (wid >= n_entities) return;

        const int s0 = offs_e[wid], s1 = offs_e[wid + 1];
        float a0[8], a1[8];
#pragma unroll
        for (int j = 0; j < 8; ++j) { a0[j] = 0.f; a1[j] = 0.f; }

        int base = s0;
        for (; base + 16 <= s1; base += 16) {
            const int tr0 = sorted_tr[base + g];
            const int tr1 = sorted_tr[base + 8 + g];
            const uint4 p0 = *reinterpret_cast<const uint4*>(
                ebf + (size_t)(tr0 & 0x1FFFF) * CH + q8 * 8);
            const uint4 p1 = *reinterpret_cast<const uint4*>(
                ebf + (size_t)(tr1 & 0x1FFFF) * CH + q8 * 8);
            const float4 w0a = wl4[(tr0 >> 17) * 16 + q8 * 2];
            const float4 w0b = wl4[(tr0 >> 17) * 16 + q8 * 2 + 1];
            const float4 w1a = wl4[(tr1 >> 17) * 16 + q8 * 2];
            const float4 w1b = wl4[(tr1 >> 17) * 16 + q8 * 2 + 1];
            a0[0] = fmaf(bf_lo(p0.x), w0a.x, a0[0]);
            a0[1] = fmaf(bf_hi(p0.x), w0a.y, a0[1]);
            a0[2] = fmaf(bf_lo(p0.y), w0a.z, a0[2]);
            a0[3] = fmaf(bf_hi(p0.y), w0a.w, a0[3]);
            a0[4] = fmaf(bf_lo(p0.z), w0b.x, a0[4]);
            a0[5] = fmaf(bf_hi(p0.z), w0b.y, a0[5]);
            a0[6] = fmaf(bf_lo(p0.w), w0b.z, a0[6]);
            a0[7] = fmaf(bf_hi(p0.w), w0b.w, a0[7]);
            a1[0] = fmaf(bf_lo(p1.x), w1a.x, a1[0]);
            a1[1] = fmaf(bf_hi(p1.x), w1a.y, a1[1]);
            a1[2] = fmaf(bf_lo(p1.y), w1a.z, a1[2]);
            a1[3] = fmaf(bf_hi(p1.y), w1a.w, a1[3]);
            a1[4] = fmaf(bf_lo(p1.z), w1b.x, a1[4]);
            a1[5] = fmaf(bf_hi(p1.z), w1b.y, a1[5]);
            a1[6] = fmaf(bf_lo(p1.w), w1b.z, a1[6]);
            a1[7] = fmaf(bf_hi(p1.w), w1b.w, a1[7]);
        }
        for (; base < s1; base += 8) {
            const int e = base + g;
            const bool valid = (e < s1);
            const int tr = valid ? sorted_tr[e] : 0;
            uint4 p; p.x = 0u; p.y = 0u; p.z = 0u; p.w = 0u;
            if (valid)
                p = *reinterpret_cast<const uint4*>(
                    ebf + (size_t)(tr & 0x1FFFF) * CH + q8 * 8);
            const float4 wa = wl4[(tr >> 17) * 16 + q8 * 2];
            const float4 wb = wl4[(tr >> 17) * 16 + q8 * 2 + 1];
            a0[0] = fmaf(bf_lo(p.x), wa.x, a0[0]);
            a0[1] = fmaf(bf_hi(p.x), wa.y, a0[1]);
            a0[2] = fmaf(bf_lo(p.y), wa.z, a0[2]);
            a0[3] = fmaf(bf_hi(p.y), wa.w, a0[3]);
            a0[4] = fmaf(bf_lo(p.z), wb.x, a0[4]);
            a0[5] = fmaf(bf_hi(p.z), wb.y, a0[5]);
            a0[6] = fmaf(bf_lo(p.w), wb.z, a0[6]);
            a0[7] = fmaf(bf_hi(p.w), wb.w, a0[7]);
        }
#pragma unroll
        for (int j = 0; j < 8; ++j) a0[j] += a1[j];

#pragma unroll
        for (int j = 0; j < 8; ++j) {
            a0[j] += __shfl_xor(a0[j], 8);
            a0[j] += __shfl_xor(a0[j], 16);
            a0[j] += __shfl_xor(a0[j], 32);
        }

        if (g == 0) {
            const int deg = s1 - s0;
            const float inv = 1.0f / (float)(deg > 0 ? deg : 1);
            float4 o0, o1;
            o0.x = a0[0] * inv; o0.y = a0[1] * inv; o0.z = a0[2] * inv; o0.w = a0[3] * inv;
            o1.x = a0[4] * inv; o1.y = a0[5] * inv; o1.z = a0[6] * inv; o1.w = a0[7] * inv;
            float* op = out_ent + (size_t)wid * CH + q8 * 8;
            *reinterpret_cast<float4*>(op)     = o0;
            *reinterpret_cast<float4*>(op + 4) = o1;
        }
    } else {
        const int wid = ((blockIdx.x - nwe) * blockDim.x + threadIdx.x) >> 6;
        if (wid >= n_users) return;

        const int s0 = offs_u[wid], s1 = offs_u[wid + 1];
        float a0[8], a1[8];
#pragma unroll
        for (int j = 0; j < 8; ++j) { a0[j] = 0.f; a1[j] = 0.f; }

        int base = s0;
        for (; base + 16 <= s1; base += 16) {
            const uint2 cv0 = upack[base + g];
            const uint2 cv1 = upack[base + 8 + g];
            const float v0 = __uint_as_float(cv0.y);
            const float v1 = __uint_as_float(cv1.y);
            const uint4 p0 = *reinterpret_cast<const uint4*>(
                ebf + (size_t)cv0.x * CH + q8 * 8);
            const uint4 p1 = *reinterpret_cast<const uint4*>(
                ebf + (size_t)cv1.x * CH + q8 * 8);
            a0[0] = fmaf(v0, bf_lo(p0.x), a0[0]);
            a0[1] = fmaf(v0, bf_hi(p0.x), a0[1]);
            a0[2] = fmaf(v0, bf_lo(p0.y), a0[2]);
            a0[3] = fmaf(v0, bf_hi(p0.y), a0[3]);
            a0[4] = fmaf(v0, bf_lo(p0.z), a0[4]);
            a0[5] = fmaf(v0, bf_hi(p0.z), a0[5]);
            a0[6] = fmaf(v0, bf_lo(p0.w), a0[6]);
            a0[7] = fmaf(v0, bf_hi(p0.w), a0[7]);
            a1[0] = fmaf(v1, bf_lo(p1.x), a1[0]);
            a1[1] = fmaf(v1, bf_hi(p1.x), a1[1]);
            a1[2] = fmaf(v1, bf_lo(p1.y), a1[2]);
            a1[3] = fmaf(v1, bf_hi(p1.y), a1[3]);
            a1[4] = fmaf(v1, bf_lo(p1.z), a1[4]);
            a1[5] = fmaf(v1, bf_hi(p1.z), a1[5]);
            a1[6] = fmaf(v1, bf_lo(p1.w), a1[6]);
            a1[7] = fmaf(v1, bf_hi(p1.w), a1[7]);
        }
        for (; base < s1; base += 8) {
            const int e = base + g;
            const bool valid = (e < s1);
            uint2 cv; cv.x = 0u; cv.y = 0u;
            if (valid) cv = upack[e];
            const float v = __uint_as_float(cv.y);   // 0 when invalid
            const uint4 p = *reinterpret_cast<const uint4*>(
                ebf + (size_t)cv.x * CH + q8 * 8);   // row 0 valid memory
            a0[0] = fmaf(v, bf_lo(p.x), a0[0]);
            a0[1] = fmaf(v, bf_hi(p.x), a0[1]);
            a0[2] = fmaf(v, bf_lo(p.y), a0[2]);
            a0[3] = fmaf(v, bf_hi(p.y), a0[3]);
            a0[4] = fmaf(v, bf_lo(p.z), a0[4]);
            a0[5] = fmaf(v, bf_hi(p.z), a0[5]);
            a0[6] = fmaf(v, bf_lo(p.w), a0[6]);
            a0[7] = fmaf(v, bf_hi(p.w), a0[7]);
        }
#pragma unroll
        for (int j = 0; j < 8; ++j) a0[j] += a1[j];

#pragma unroll
        for (int j = 0; j < 8; ++j) {
            a0[j] += __shfl_xor(a0[j], 8);
            a0[j] += __shfl_xor(a0[j], 16);
            a0[j] += __shfl_xor(a0[j], 32);
        }

        if (g == 0) {
            float4 o0, o1;
            o0.x = a0[0]; o0.y = a0[1]; o0.z = a0[2]; o0.w = a0[3];
            o1.x = a0[4]; o1.y = a0[5]; o1.z = a0[6]; o1.w = a0[7];
            float* op = out_user + (size_t)wid * CH + q8 * 8;
            *reinterpret_cast<float4*>(op)     = o0;
            *reinterpret_cast<float4*>(op + 4) = o1;
        }
    }
}

// =========================================================================
// Tier-2 (CSR path): sliced hist/scatter
// =========================================================================
__global__ void hist_sliced_kernel(const int* __restrict__ keys,
                                   int* __restrict__ counts, int n, unsigned smul) {
    const int slice = blockIdx.x & (NSLICE - 1);
    const int rb    = blockIdx.x >> 3;
    const int nrb   = gridDim.x >> 3;
    const int per   = (n + nrb - 1) / nrb;
    const int i0    = rb * per;
    const int i1    = min(i0 + per, n);
    for (int i = i0 + (int)threadIdx.x; i < i1; i += blockDim.x) {
        const int k = keys[i];
        if ((int)__umulhi((unsigned)k, smul) == slice)
            atomicAdd(&counts[k], 1);
    }
}

__global__ void scatter_e_sliced_kernel(const int* __restrict__ edge_index,
                                        const int* __restrict__ edge_type,
                                        const int* __restrict__ offs,
                                        int* __restrict__ cursor,
                                        int* __restrict__ sorted_tr,
                                        int E, int n_rel, unsigned smul) {
    const int slice = blockIdx.x & (NSLICE - 1);
    const int rb    = blockIdx.x >> 3;
    const int nrb   = gridDim.x >> 3;
    const int per   = (E + nrb - 1) / nrb;
    const int e0    = rb * per;
    const int e1    = min(e0 + per, E);
    for (int e = e0 + (int)threadIdx.x; e < e1; e += blockDim.x) {
        const int h = edge_index[e];
        if ((int)__umulhi((unsigned)h, smul) != slice) continue;
        const int t = edge_index[(size_t)E + e];
        int r = edge_type[e] - 1;
        if (r < 0) r += n_rel;
        const int pos = offs[h] + atomicAdd(&cursor[h], 1);
        sorted_tr[pos] = t | (r << 17);
    }
}

__global__ void scatter_u_sliced_kernel(const int* __restrict__ irows,
                                        const int* __restrict__ icols,
                                        const float* __restrict__ ivals,
                                        const int* __restrict__ offs,
                                        int* __restrict__ cursor,
                                        uint2* __restrict__ upack,
                                        int NNZ, unsigned smul) {
    const int slice = blockIdx.x & (NSLICE - 1);
    const int rb    = blockIdx.x >> 3;
    const int nrb   = gridDim.x >> 3;
    const int per   = (NNZ + nrb - 1) / nrb;
    const int i0    = rb * per;
    const int i1    = min(i0 + per, NNZ);
    for (int i = i0 + (int)threadIdx.x; i < i1; i += blockDim.x) {
        const int u = irows[i];
        if ((int)__umulhi((unsigned)u, smul) != slice) continue;
        const int pos = offs[u] + atomicAdd(&cursor[u], 1);
        uint2 cv;
        cv.x = (unsigned)icols[i];
        cv.y = __float_as_uint(ivals[i]);
        upack[pos] = cv;
    }
}

// =========================================================================
// Tier-3 (atomic fallback)
// =========================================================================
__global__ void kg_agg_atomic_kernel(const float* __restrict__ emb,
                                     const float* __restrict__ region_ent,
                                     const int* __restrict__ edge_index,
                                     const int* __restrict__ edge_type,
                                     const float* __restrict__ weight,
                                     float* __restrict__ out_ent,
                                     float* __restrict__ counts,
                                     int E, int n_rel) {
    const long long gid = (long long)blockIdx.x * blockDim.x + threadIdx.x;
    const long long e = gid >> 6;
    if (e >= E) return;
    const int c = (int)gid & 63;
    const int h = edge_index[e];
    const int t = edge_index[(size_t)E + e];
    int r = edge_type[e] - 1;
    if (r < 0) r += n_rel;
    const float v = ent_val(emb, region_ent, t, c) * weight[(size_t)r * CH + c];
    unsafeAtomicAdd(out_ent + (size_t)h * CH + c, v);
    if (c == 0) unsafeAtomicAdd(counts + h, 1.0f);
}

__global__ void user_agg_atomic_kernel(const float* __restrict__ emb,
                                       const float* __restrict__ region_ent,
                                       const int* __restrict__ irows,
                                       const int* __restrict__ icols,
                                       const float* __restrict__ ivals,
                                       float* __restrict__ out_user, int NNZ) {
    const long long gid = (long long)blockIdx.x * blockDim.x + threadIdx.x;
    const long long i = gid >> 6;
    if (i >= NNZ) return;
    const int c = (int)gid & 63;
    const float v = ivals[i] * ent_val(emb, region_ent, icols[i], c);
    unsafeAtomicAdd(out_user + (size_t)irows[i] * CH + c, v);
}

__global__ void finalize_kernel(float* __restrict__ out_ent,
                                const float* __restrict__ counts, int n_entities) {
    const int gid = blockIdx.x * blockDim.x + threadIdx.x;
    if (gid >= n_entities * CH) return;
    out_ent[gid] /= fmaxf(counts[gid >> 6], 1.0f);
}

// =========================================================================
extern "C" void kernel_launch(void* const* d_in, const int* in_sizes, int n_in,
                              void* d_out, int out_size, void* d_ws, size_t ws_size,
                              hipStream_t stream) {
    const float* entity_emb = (const float*)d_in[0];
    const int*   edge_index = (const int*)d_in[2];
    const int*   edge_type  = (const int*)d_in[3];
    const int*   irows      = (const int*)d_in[4];
    const int*   icols      = (const int*)d_in[5];
    const float* ivals      = (const float*)d_in[6];
    const float* Wreg       = (const float*)d_in[7];
    const float* weight     = (const float*)d_in[8];

    const int n_entities = in_sizes[0] / CH;
    const int n_users    = in_sizes[1] / CH;
    const int E          = in_sizes[3];
    const int NNZ        = in_sizes[4];
    const int n_rel      = in_sizes[8] / CH;

    float* out_ent  = (float*)d_out;
    float* out_user = out_ent + (size_t)n_entities * CH;

    const int NBUK_E = (n_entities + 63) >> 6;
    const int NBUK_U = (n_users + 63) >> 6;
    const int n_e = NBUK_E * NB;
    const int n_u = NBUK_U * NB;
    const int nbse = (n_e + SCAN_B - 1) / SCAN_B;
    const int nbsu = (n_u + SCAN_B - 1) / SCAN_B;

    // ---- tier-1 (bucket) layout ----
    char* w = (char*)d_ws;
    auto take = [&](size_t bytes) {
        char* p = w;
        w += (bytes + 7) & ~(size_t)7;
        return p;
    };
    float*    region_ent = (float*)take((size_t)RN * CH * 4);
    ushort_t* e_t        = (ushort_t*)take((size_t)CH * KP * 2);
    ushort_t* ebf        = (ushort_t*)take((size_t)n_entities * CH * 2);
    int*      sorted_tr  = (int*)take((size_t)E * 4);
    uint2*    upack      = (uint2*)take((size_t)NNZ * 8);
    int*      offs_e     = (int*)take((size_t)(n_entities + 1) * 4);
    int*      offs_u     = (int*)take((size_t)(n_users + 1) * 4);
    int*      bsums_e    = (int*)take(512 * 4);
    int*      bsums_u    = (int*)take(512 * 4);
    int*      hist_e     = (int*)take((size_t)n_e * 4);
    int*      exbase_e   = (int*)take((size_t)(n_e + 1) * 4);
    int*      hist_u     = (int*)take((size_t)n_u * 4);
    int*      exbase_u   = (int*)take((size_t)(n_u + 1) * 4);
    int*      pcode_e    = (int*)take((size_t)E * 4);
    uint2*    pcode_u    = (uint2*)take((size_t)NNZ * 8);
    const size_t need_bucket = (size_t)(w - (char*)d_ws);

    const bool common_ok = (n_entities < (1 << 17)) && (n_rel <= 32);
    const bool use_bucket = common_ok && (ws_size >= need_bucket) &&
                            (NBUK_E <= MAXBUK) && (NBUK_U <= MAXBUK) &&
                            (nbse <= 512) && (nbsu <= 512);

    // ---- tier-2 (csr) layout ----
    char* w2 = (char*)d_ws;
    auto take2 = [&](size_t bytes) {
        char* p = w2;
        w2 += (bytes + 7) & ~(size_t)7;
        return p;
    };
    float*    c_region  = (float*)take2((size_t)RN * CH * 4);
    int*      c_offs_e  = (int*)take2((size_t)(n_entities + 1) * 4);
    int*      c_cur_e   = (int*)take2((size_t)n_entities * 4);
    int*      c_offs_u  = (int*)take2((size_t)(n_users + 1) * 4);
    int*      c_cur_u   = (int*)take2((size_t)n_users * 4);
    int*      c_bsums   = (int*)take2(512 * 4);
    int*      c_sorted  = (int*)take2((size_t)E * 4);
    uint2*    c_upack   = (uint2*)take2((size_t)NNZ * 8);
    ushort_t* c_et      = (ushort_t*)take2((size_t)CH * KP * 2);
    ushort_t* c_ebf     = (ushort_t*)take2((size_t)n_entities * CH * 2);
    const size_t need_csr = (size_t)(w2 - (char*)d_ws);
    const int nb_e = (n_entities + SCAN_B - 1) / SCAN_B;
    const int nb_u = (n_users + SCAN_B - 1) / SCAN_B;
    const bool use_csr = common_ok && (ws_size >= need_csr) &&
                         (nb_e <= 512) && (nb_u <= 512);

    const int nwe = (n_entities + 3) / 4;
    const int nwu = (n_users + 3) / 4;

    if (use_bucket) {
        // fused region init + e_t build
        region_init_et_kernel<<<IB_INIT + EB_ET, 256, 0, stream>>>(
            entity_emb, region_ent, e_t);
        region_gemm_mfma_kernel<<<MT_BLKS * KCHUNKS, 256, 0, stream>>>(
            Wreg, e_t, region_ent);
        {
            const int tot = n_entities * (CH / 8);
            build_ebf_kernel<<<(tot + 255) / 256, 256, 0, stream>>>(
                entity_emb, region_ent, ebf, n_entities);
        }

        bucket_hist2_kernel<<<2 * NB, T1, 0, stream>>>(
            edge_index, E, NBUK_E, irows, NNZ, NBUK_U, hist_e, hist_u);

        scan_block2_kernel<<<nbse + nbsu, SCAN_B, 0, stream>>>(
            hist_e, exbase_e, bsums_e, n_e, nbse,
            hist_u, exbase_u, bsums_u, n_u);
        scan_top2_kernel<<<2, 512, 0, stream>>>(bsums_e, nbse, bsums_u, nbsu);
        scan_add2_kernel<<<nbse + nbsu, SCAN_B, 0, stream>>>(
            exbase_e, bsums_e, n_e, nbse, exbase_u, bsums_u, n_u);

        pass2_combined_kernel<<<2 * NB, T1, 0, stream>>>(
            edge_index, edge_type, exbase_e, pcode_e, E, n_rel, NBUK_E,
            irows, icols, ivals, exbase_u, pcode_u, NNZ, NBUK_U);

        bucket_sort2_kernel<<<NBUK_E + NBUK_U, 256, 0, stream>>>(
            pcode_e, exbase_e, sorted_tr, offs_e, n_entities, NBUK_E,
            pcode_u, exbase_u, upack, offs_u, n_users, NBUK_U);

        gather2_kernel<<<nwe + nwu, 256, n_rel * CH * 4, stream>>>(
            ebf, sorted_tr, offs_e, weight, out_ent, n_entities, n_rel, nwe,
            upack, offs_u, out_user, n_users);
    } else if (use_csr) {
        const unsigned smul_e = (unsigned)((8ULL << 32) / (unsigned long long)n_entities);
        const unsigned smul_u = (unsigned)((8ULL << 32) / (unsigned long long)n_users);

        region_init_et_kernel<<<IB_INIT + EB_ET, 256, 0, stream>>>(
            entity_emb, c_region, c_et);
        region_gemm_mfma_kernel<<<MT_BLKS * KCHUNKS, 256, 0, stream>>>(
            Wreg, c_et, c_region);
        {
            const int tot = n_entities * (CH / 8);
            build_ebf_kernel<<<(tot + 255) / 256, 256, 0, stream>>>(
                entity_emb, c_region, c_ebf, n_entities);
        }

        hipMemsetAsync(c_cur_e, 0, (size_t)n_entities * 4, stream);
        hipMemsetAsync(c_cur_u, 0, (size_t)n_users * 4, stream);
        hist_sliced_kernel<<<NSLICE * SLICE_RB, 256, 0, stream>>>(
            edge_index, c_cur_e, E, smul_e);
        hist_sliced_kernel<<<NSLICE * SLICE_RB, 256, 0, stream>>>(
            irows, c_cur_u, NNZ, smul_u);

        scan_block_kernel<<<nb_e, SCAN_B, 0, stream>>>(c_cur_e, c_offs_e, c_bsums, n_entities);
        scan_top_kernel<<<1, 512, 0, stream>>>(c_bsums, nb_e);
        scan_add_kernel<<<nb_e, SCAN_B, 0, stream>>>(c_offs_e, c_bsums, n_entities);

        scan_block_kernel<<<nb_u, SCAN_B, 0, stream>>>(c_cur_u, c_offs_u, c_bsums, n_users);
        scan_top_kernel<<<1, 512, 0, stream>>>(c_bsums, nb_u);
        scan_add_kernel<<<nb_u, SCAN_B, 0, stream>>>(c_offs_u, c_bsums, n_users);

        hipMemsetAsync(c_cur_e, 0, (size_t)n_entities * 4, stream);
        hipMemsetAsync(c_cur_u, 0, (size_t)n_users * 4, stream);
        scatter_e_sliced_kernel<<<NSLICE * SLICE_RB, 256, 0, stream>>>(
            edge_index, edge_type, c_offs_e, c_cur_e, c_sorted, E, n_rel, smul_e);
        scatter_u_sliced_kernel<<<NSLICE * SLICE_RB, 256, 0, stream>>>(
            irows, icols, ivals, c_offs_u, c_cur_u, c_upack, NNZ, smul_u);

        gather2_kernel<<<nwe + nwu, 256, n_rel * CH * 4, stream>>>(
            c_ebf, c_sorted, c_offs_e, weight, out_ent, n_entities, n_rel, nwe,
            c_upack, c_offs_u, out_user, n_users);
    } else {
        // tier-3: atomic fallback
        float* region3 = (float*)d_ws;
        float* counts  = region3 + (size_t)RN * CH;
        region_init_kernel<<<(RN * CH / 4 + 255) / 256, 256, 0, stream>>>(entity_emb, region3);
        region_gemm_kernel<<<ROW_TILES * KSPLIT, 256, 0, stream>>>(
            entity_emb, Wreg, region3);
        hipMemsetAsync(d_out, 0, (size_t)out_size * sizeof(float), stream);
        hipMemsetAsync(counts, 0, (size_t)n_entities * sizeof(float), stream);
        {
            const long long tot = (long long)E * CH;
            kg_agg_atomic_kernel<<<(int)((tot + 255) / 256), 256, 0, stream>>>(
                entity_emb, region3, edge_index, edge_type, weight,
                out_ent, counts, E, n_rel);
        }
        {
            const long long tot = (long long)NNZ * CH;
            user_agg_atomic_kernel<<<(int)((tot + 255) / 256), 256, 0, stream>>>(
                entity_emb, region3, irows, icols, ivals, out_user, NNZ);
        }
        finalize_kernel<<<(n_entities * CH + 255) / 256, 256, 0, stream>>>(
            out_ent, counts, n_entities);
    }
}

// Round 27
// 175.913 us; speedup vs baseline: 1.1149x; 1.0256x over previous
//
#include <hip/hip_runtime.h>
#include <hip/hip_bf16.h>

// Problem constants (from reference source)
#define REGION_R0 42033
#define REGION_R1 44630
#define RN        (REGION_R1 - REGION_R0)   // 2597
#define CH        64
#define KSPLIT    32
#define ROW_TILES ((RN + 31) / 32)          // 82
#define SCAN_B    256
#define NSLICE    8
#define SLICE_RB  256                        // tier-2 grid

// bucket partition geometry
#define NB        64                         // range-blocks: 16-entry (64B) exclusive runs
#define T1        1024                       // 16 waves/block
#define MAXBUK    2048

// MFMA region-gemm geometry
#define KTT       82
#define KP        (KTT * 32)                 // 2624
#define PERCHUNK  6
#define KCHUNKS   14
#define MT_TILES  163
#define MT_BLKS   41

typedef unsigned short ushort_t;
typedef short  bfrag8 __attribute__((ext_vector_type(8)));
typedef float  f32x4v __attribute__((ext_vector_type(4)));

__device__ __forceinline__ unsigned pack2bf(float a, float b) {
    unsigned ua = __float_as_uint(a);
    unsigned ub = __float_as_uint(b);
    ua += 0x7fffu + ((ua >> 16) & 1u);   // RNE
    ub += 0x7fffu + ((ub >> 16) & 1u);
    return ((ua >> 16) & 0xffffu) | (ub & 0xffff0000u);
}

__device__ __forceinline__ float bf_lo(unsigned u) { return __uint_as_float(u << 16); }
__device__ __forceinline__ float bf_hi(unsigned u) { return __uint_as_float(u & 0xffff0000u); }

// =========================================================================
// Fused region init + e_t build (R26-proven)
// =========================================================================
#define IB_INIT   ((RN * CH / 4 + 255) / 256)     // 163
#define EB_ET     ((CH * (KP / 8) + 255) / 256)   // 82

__global__ void region_init_et_kernel(const float* __restrict__ emb,
                                      float* __restrict__ region_ent,
                                      ushort_t* __restrict__ e_t) {
    if ((int)blockIdx.x < IB_INIT) {
        const int gid = blockIdx.x * 256 + threadIdx.x;
        if (gid >= RN * CH / 4) return;
        const float4 v = reinterpret_cast<const float4*>(emb + (size_t)REGION_R0 * CH)[gid];
        float4 o;
        o.x = 0.8f * v.x; o.y = 0.8f * v.y; o.z = 0.8f * v.z; o.w = 0.8f * v.w;
        reinterpret_cast<float4*>(region_ent)[gid] = o;
    } else {
        const int gid = (blockIdx.x - IB_INIT) * 256 + threadIdx.x;
        if (gid >= CH * (KP / 8)) return;
        const int c  = gid / (KP / 8);
        const int k8 = gid - c * (KP / 8);
        const int kb = k8 * 8;
        float v[8];
#pragma unroll
        for (int j = 0; j < 8; ++j) {
            const int k = kb + j;
            v[j] = (k < RN) ? emb[(size_t)(REGION_R0 + k) * CH + c] : 0.0f;
        }
        uint4 o;
        o.x = pack2bf(v[0], v[1]); o.y = pack2bf(v[2], v[3]);
        o.z = pack2bf(v[4], v[5]); o.w = pack2bf(v[6], v[7]);
        *reinterpret_cast<uint4*>(e_t + (size_t)c * KP + kb) = o;
    }
}

// =========================================================================
// MFMA region GEMM (R14-verified, absmax 0.25)
// =========================================================================
__global__ void region_gemm_mfma_kernel(const float* __restrict__ W,
                                        const ushort_t* __restrict__ e_t,
                                        float* __restrict__ region_ent) {
    const int wv    = threadIdx.x >> 6;
    const int lane  = threadIdx.x & 63;
    const int blk_m = blockIdx.x / KCHUNKS;
    const int kc    = blockIdx.x - blk_m * KCHUNKS;
    const int mt    = blk_m * 4 + wv;
    if (mt >= MT_TILES) return;
    const int l15 = lane & 15;
    const int lg  = lane >> 4;

    int arow = mt * 16 + l15;
    if (arow >= RN) arow = RN - 1;
    const float* wrow = W + (size_t)arow * RN;

    const int kt0 = kc * PERCHUNK;
    const int kt1 = (kt0 + PERCHUNK < KTT) ? (kt0 + PERCHUNK) : KTT;

    f32x4v acc[4];
#pragma unroll
    for (int n = 0; n < 4; ++n) acc[n] = (f32x4v){0.f, 0.f, 0.f, 0.f};

    for (int kt = kt0; kt < kt1; ++kt) {
        const int kb = kt * 32 + lg * 8;
        union { uint4 u; bfrag8 f; } A;
        if (kb + 8 <= RN) {
            float v0 = wrow[kb + 0], v1 = wrow[kb + 1];
            float v2 = wrow[kb + 2], v3 = wrow[kb + 3];
            float v4 = wrow[kb + 4], v5 = wrow[kb + 5];
            float v6 = wrow[kb + 6], v7 = wrow[kb + 7];
            A.u.x = pack2bf(v0, v1); A.u.y = pack2bf(v2, v3);
            A.u.z = pack2bf(v4, v5); A.u.w = pack2bf(v6, v7);
        } else {
            float v[8];
#pragma unroll
            for (int j = 0; j < 8; ++j) {
                const int k = kb + j;
                v[j] = (k < RN) ? wrow[k] : 0.0f;
            }
            A.u.x = pack2bf(v[0], v[1]); A.u.y = pack2bf(v[2], v[3]);
            A.u.z = pack2bf(v[4], v[5]); A.u.w = pack2bf(v[6], v[7]);
        }
#pragma unroll
        for (int n = 0; n < 4; ++n) {
            const bfrag8 B = *reinterpret_cast<const bfrag8*>(
                e_t + (size_t)(n * 16 + l15) * KP + kb);
            acc[n] = __builtin_amdgcn_mfma_f32_16x16x32_bf16(A.f, B, acc[n], 0, 0, 0);
        }
    }

#pragma unroll
    for (int n = 0; n < 4; ++n) {
#pragma unroll
        for (int j = 0; j < 4; ++j) {
            const int row = mt * 16 + lg * 4 + j;
            if (row < RN)
                unsafeAtomicAdd(region_ent + (size_t)row * CH + n * 16 + l15,
                                0.2f * acc[n][j]);
        }
    }
}

// =========================================================================
// VALU region GEMM (tier-3 fallback only)
// =========================================================================
__global__ void region_init_kernel(const float* __restrict__ emb,
                                   float* __restrict__ region_ent) {
    const int gid = blockIdx.x * blockDim.x + threadIdx.x;
    if (gid >= RN * CH / 4) return;
    const float4 v = reinterpret_cast<const float4*>(emb + (size_t)REGION_R0 * CH)[gid];
    float4 o;
    o.x = 0.8f * v.x; o.y = 0.8f * v.y; o.z = 0.8f * v.z; o.w = 0.8f * v.w;
    reinterpret_cast<float4*>(region_ent)[gid] = o;
}

__global__ void region_gemm_kernel(const float* __restrict__ emb,
                                   const float* __restrict__ W,
                                   float* __restrict__ region_ent) {
    const int wave = threadIdx.x >> 6;
    const int c    = threadIdx.x & 63;
    const int rt   = blockIdx.x / KSPLIT;
    const int ks   = blockIdx.x - rt * KSPLIT;
    const int base = rt * 32 + wave * 8;
    if (base >= RN) return;

    const int k0 = (RN * ks) / KSPLIT;
    const int k1 = (RN * (ks + 1)) / KSPLIT;

    const float* wp[8];
#pragma unroll
    for (int r = 0; r < 8; ++r) {
        int row = base + r;
        if (row >= RN) row = RN - 1;
        row = __builtin_amdgcn_readfirstlane(row);
        wp[r] = W + (size_t)row * RN;
    }
    const float* ep = emb + (size_t)REGION_R0 * CH + c;

    float acc[8];
#pragma unroll
    for (int r = 0; r < 8; ++r) acc[r] = 0.0f;

    int k = k0;
    for (; k + 4 <= k1; k += 4) {
        const float e0 = ep[(size_t)(k + 0) * CH];
        const float e1 = ep[(size_t)(k + 1) * CH];
        const float e2 = ep[(size_t)(k + 2) * CH];
        const float e3 = ep[(size_t)(k + 3) * CH];
#pragma unroll
        for (int r = 0; r < 8; ++r) {
            const float* wr = wp[r];
            float a = acc[r];
            a = fmaf(wr[k + 0], e0, a);
            a = fmaf(wr[k + 1], e1, a);
            a = fmaf(wr[k + 2], e2, a);
            a = fmaf(wr[k + 3], e3, a);
            acc[r] = a;
        }
    }
    for (; k < k1; ++k) {
        const float e = ep[(size_t)k * CH];
#pragma unroll
        for (int r = 0; r < 8; ++r) acc[r] = fmaf(wp[r][k], e, acc[r]);
    }
#pragma unroll
    for (int r = 0; r < 8; ++r) {
        const int row = base + r;
        if (row < RN)
            unsafeAtomicAdd(region_ent + (size_t)row * CH + c, 0.2f * acc[r]);
    }
}

__device__ __forceinline__ float ent_val(const float* __restrict__ emb,
                                         const float* __restrict__ region_ent,
                                         int row, int c) {
    const float* p = (row >= REGION_R0 && row < REGION_R1)
                         ? (region_ent + (size_t)(row - REGION_R0) * CH + c)
                         : (emb + (size_t)row * CH + c);
    return *p;
}

__device__ __forceinline__ const float* ent_row(const float* __restrict__ emb,
                                                const float* __restrict__ region_ent,
                                                int row) {
    return (row >= REGION_R0 && row < REGION_R1)
               ? (region_ent + (size_t)(row - REGION_R0) * CH)
               : (emb + (size_t)row * CH);
}

// =========================================================================
// bf16 entity table (region rows baked in)
// =========================================================================
__global__ void build_ebf_kernel(const float* __restrict__ emb,
                                 const float* __restrict__ region_ent,
                                 ushort_t* __restrict__ ebf,
                                 int n_entities) {
    const int gid = blockIdx.x * blockDim.x + threadIdx.x;
    if (gid >= n_entities * (CH / 8)) return;
    const int row = gid >> 3;
    const int co  = (gid & 7) * 8;
    const float* rp = ent_row(emb, region_ent, row) + co;
    const float4 a = *reinterpret_cast<const float4*>(rp);
    const float4 b = *reinterpret_cast<const float4*>(rp + 4);
    uint4 o;
    o.x = pack2bf(a.x, a.y);
    o.y = pack2bf(a.z, a.w);
    o.z = pack2bf(b.x, b.y);
    o.w = pack2bf(b.z, b.w);
    *reinterpret_cast<uint4*>(ebf + (size_t)row * CH + co) = o;
}

// =========================================================================
// Combined bucket hist (R27: x8 unrolled key loads)
// =========================================================================
__global__ void bucket_hist2_kernel(const int* __restrict__ ekeys, int ne, int nbe,
                                    const int* __restrict__ ukeys, int nu, int nbu,
                                    int* __restrict__ hist_e,
                                    int* __restrict__ hist_u) {
    __shared__ int lh[MAXBUK];
    const bool is_u = (blockIdx.x >= NB);
    const int  rb   = is_u ? (blockIdx.x - NB) : blockIdx.x;
    const int* keys = is_u ? ukeys : ekeys;
    const int  n    = is_u ? nu : ne;
    const int  nbuk = is_u ? nbu : nbe;
    int* hist       = is_u ? hist_u : hist_e;

    for (int i = threadIdx.x; i < nbuk; i += T1) lh[i] = 0;
    __syncthreads();
    const int chunk = (n + NB - 1) / NB;
    const int i0 = rb * chunk;
    const int i1 = min(i0 + chunk, n);
    int i = i0 + (int)threadIdx.x;
    for (; i + 7 * T1 < i1; i += 8 * T1) {
        int k[8];
#pragma unroll
        for (int j = 0; j < 8; ++j) k[j] = keys[i + j * T1];
#pragma unroll
        for (int j = 0; j < 8; ++j) atomicAdd(&lh[k[j] >> 6], 1);
    }
    for (; i < i1; i += T1)
        atomicAdd(&lh[keys[i] >> 6], 1);
    __syncthreads();
    for (int b = threadIdx.x; b < nbuk; b += T1)
        hist[(size_t)b * NB + rb] = lh[b];
}

// =========================================================================
// Fused two-array scans (R26-proven)
// =========================================================================
__global__ void scan_block2_kernel(const int* __restrict__ ce, int* __restrict__ oe,
                                   int* __restrict__ bse, int ne2, int nbse,
                                   const int* __restrict__ cu, int* __restrict__ ou,
                                   int* __restrict__ bsu, int nu2) {
    __shared__ int s[SCAN_B];
    const bool is_u = ((int)blockIdx.x >= nbse);
    const int  rb   = is_u ? (blockIdx.x - nbse) : blockIdx.x;
    const int* counts = is_u ? cu : ce;
    int* offs  = is_u ? ou : oe;
    int* bsums = is_u ? bsu : bse;
    const int n = is_u ? nu2 : ne2;

    const int i = rb * SCAN_B + threadIdx.x;
    s[threadIdx.x] = (i < n) ? counts[i] : 0;
    __syncthreads();
    for (int d = 1; d < SCAN_B; d <<= 1) {
        const int t = (threadIdx.x >= d) ? s[threadIdx.x - d] : 0;
        __syncthreads();
        s[threadIdx.x] += t;
        __syncthreads();
    }
    if (i < n) offs[i + 1] = s[threadIdx.x];
    if (threadIdx.x == SCAN_B - 1) bsums[rb] = s[threadIdx.x];
    if (rb == 0 && threadIdx.x == 0) offs[0] = 0;
}

__global__ void scan_top2_kernel(int* __restrict__ bse, int nbe2,
                                 int* __restrict__ bsu, int nbu2) {
    __shared__ int s[512];
    int* bsums = blockIdx.x ? bsu : bse;
    const int nb = blockIdx.x ? nbu2 : nbe2;
    s[threadIdx.x] = (threadIdx.x < (unsigned)nb) ? bsums[threadIdx.x] : 0;
    __syncthreads();
    for (int d = 1; d < 512; d <<= 1) {
        const int t = (threadIdx.x >= d) ? s[threadIdx.x - d] : 0;
        __syncthreads();
        s[threadIdx.x] += t;
        __syncthreads();
    }
    if (threadIdx.x < (unsigned)nb) bsums[threadIdx.x] = s[threadIdx.x];
}

__global__ void scan_add2_kernel(int* __restrict__ oe, const int* __restrict__ bse,
                                 int ne2, int nbse,
                                 int* __restrict__ ou, const int* __restrict__ bsu,
                                 int nu2) {
    const bool is_u = ((int)blockIdx.x >= nbse);
    const int  rb   = is_u ? (blockIdx.x - nbse) : blockIdx.x;
    if (rb == 0) return;
    int* offs = is_u ? ou : oe;
    const int* bsums = is_u ? bsu : bse;
    const int n = is_u ? nu2 : ne2;
    const int i = rb * SCAN_B + threadIdx.x;
    if (i < n) offs[i + 1] += bsums[rb - 1];
}

// tier-2 single-array scans
__global__ void scan_block_kernel(const int* __restrict__ counts, int* __restrict__ offs,
                                  int* __restrict__ bsums, int n) {
    __shared__ int s[SCAN_B];
    const int i = blockIdx.x * SCAN_B + threadIdx.x;
    s[threadIdx.x] = (i < n) ? counts[i] : 0;
    __syncthreads();
    for (int d = 1; d < SCAN_B; d <<= 1) {
        const int t = (threadIdx.x >= d) ? s[threadIdx.x - d] : 0;
        __syncthreads();
        s[threadIdx.x] += t;
        __syncthreads();
    }
    if (i < n) offs[i + 1] = s[threadIdx.x];
    if (threadIdx.x == SCAN_B - 1) bsums[blockIdx.x] = s[threadIdx.x];
    if (blockIdx.x == 0 && threadIdx.x == 0) offs[0] = 0;
}

__global__ void scan_top_kernel(int* __restrict__ bsums, int nb) {
    __shared__ int s[512];
    s[threadIdx.x] = (threadIdx.x < (unsigned)nb) ? bsums[threadIdx.x] : 0;
    __syncthreads();
    for (int d = 1; d < 512; d <<= 1) {
        const int t = (threadIdx.x >= d) ? s[threadIdx.x - d] : 0;
        __syncthreads();
        s[threadIdx.x] += t;
        __syncthreads();
    }
    if (threadIdx.x < (unsigned)nb) bsums[threadIdx.x] = s[threadIdx.x];
}

__global__ void scan_add_kernel(int* __restrict__ offs, const int* __restrict__ bsums, int n) {
    if (blockIdx.x == 0) return;
    const int i = blockIdx.x * SCAN_B + threadIdx.x;
    if (i < n) offs[i + 1] += bsums[blockIdx.x - 1];
}

// =========================================================================
// Combined pass2 (R27: x8 unrolled chains)
// =========================================================================
__global__ void pass2_combined_kernel(const int* __restrict__ edge_index,
                                      const int* __restrict__ edge_type,
                                      const int* __restrict__ exbase_e,
                                      int* __restrict__ pcode_e,
                                      int E, int n_rel, int nbe,
                                      const int* __restrict__ irows,
                                      const int* __restrict__ icols,
                                      const float* __restrict__ ivals,
                                      const int* __restrict__ exbase_u,
                                      uint2* __restrict__ pcode_u,
                                      int NNZ, int nbu) {
    __shared__ int cur[MAXBUK];
    __shared__ int exb[MAXBUK];
    const bool is_u = (blockIdx.x >= NB);
    const int  rb   = is_u ? (blockIdx.x - NB) : blockIdx.x;
    const int  nbuk = is_u ? nbu : nbe;
    const int* exbase = is_u ? exbase_u : exbase_e;

    for (int i = threadIdx.x; i < nbuk; i += T1) {
        cur[i] = 0;
        exb[i] = exbase[(size_t)i * NB + rb];
    }
    __syncthreads();

    if (!is_u) {
        const int chunk = (E + NB - 1) / NB;
        const int i0 = rb * chunk;
        const int i1 = min(i0 + chunk, E);
        int e = i0 + (int)threadIdx.x;
        for (; e + 7 * T1 < i1; e += 8 * T1) {
            int h[8], t[8], r[8], b[8], l[8];
#pragma unroll
            for (int j = 0; j < 8; ++j) h[j] = edge_index[e + j * T1];
#pragma unroll
            for (int j = 0; j < 8; ++j) t[j] = edge_index[(size_t)E + e + j * T1];
#pragma unroll
            for (int j = 0; j < 8; ++j) {
                r[j] = edge_type[e + j * T1] - 1;
                if (r[j] < 0) r[j] += n_rel;
            }
#pragma unroll
            for (int j = 0; j < 8; ++j) {
                b[j] = h[j] >> 6;
                l[j] = atomicAdd(&cur[b[j]], 1);
            }
#pragma unroll
            for (int j = 0; j < 8; ++j)
                pcode_e[exb[b[j]] + l[j]] = ((h[j] & 63) << 22) | (r[j] << 17) | t[j];
        }
        for (; e < i1; e += T1) {
            const int h = edge_index[e];
            const int b = h >> 6;
            const int loc = atomicAdd(&cur[b], 1);
            const int pos = exb[b] + loc;
            const int t = edge_index[(size_t)E + e];
            int r = edge_type[e] - 1;
            if (r < 0) r += n_rel;
            pcode_e[pos] = ((h & 63) << 22) | (r << 17) | t;
        }
    } else {
        const int chunk = (NNZ + NB - 1) / NB;
        const int i0 = rb * chunk;
        const int i1 = min(i0 + chunk, NNZ);
        int i = i0 + (int)threadIdx.x;
        for (; i + 7 * T1 < i1; i += 8 * T1) {
            int u[8], c[8], b[8], l[8];
            float v[8];
#pragma unroll
            for (int j = 0; j < 8; ++j) u[j] = irows[i + j * T1];
#pragma unroll
            for (int j = 0; j < 8; ++j) c[j] = icols[i + j * T1];
#pragma unroll
            for (int j = 0; j < 8; ++j) v[j] = ivals[i + j * T1];
#pragma unroll
            for (int j = 0; j < 8; ++j) {
                b[j] = u[j] >> 6;
                l[j] = atomicAdd(&cur[b[j]], 1);
            }
#pragma unroll
            for (int j = 0; j < 8; ++j) {
                uint2 cv;
                cv.x = ((unsigned)(u[j] & 63) << 17) | (unsigned)c[j];
                cv.y = __float_as_uint(v[j]);
                pcode_u[exb[b[j]] + l[j]] = cv;
            }
        }
        for (; i < i1; i += T1) {
            const int u = irows[i];
            const int b = u >> 6;
            const int loc = atomicAdd(&cur[b], 1);
            const int pos = exb[b] + loc;
            uint2 cv;
            cv.x = ((unsigned)(u & 63) << 17) | (unsigned)icols[i];
            cv.y = __float_as_uint(ivals[i]);
            pcode_u[pos] = cv;
        }
    }
}

// =========================================================================
// Combined per-bucket counting sort (R20-proven)
// =========================================================================
__global__ void bucket_sort2_kernel(const int* __restrict__ pcode_e,
                                    const int* __restrict__ exbase_e,
                                    int* __restrict__ sorted_tr,
                                    int* __restrict__ offs_e,
                                    int n_entities, int nbe,
                                    const uint2* __restrict__ pcode_u,
                                    const int* __restrict__ exbase_u,
                                    uint2* __restrict__ upack,
                                    int* __restrict__ offs_u,
                                    int n_users, int nbu) {
    __shared__ int cnt[64];
    __shared__ int off[64];
    __shared__ int cur[64];
    const bool is_u = (blockIdx.x >= (unsigned)nbe);
    const int  b    = is_u ? (blockIdx.x - nbe) : blockIdx.x;
    const int* exbase = is_u ? exbase_u : exbase_e;
    const int bstart = exbase[(size_t)b * NB];
    const int bend   = exbase[(size_t)(b + 1) * NB];
    if (threadIdx.x < 64) { cnt[threadIdx.x] = 0; cur[threadIdx.x] = 0; }
    __syncthreads();

    if (!is_u) {
        for (int i = bstart + (int)threadIdx.x; i < bend; i += blockDim.x)
            atomicAdd(&cnt[(pcode_e[i] >> 22) & 63], 1);
    } else {
        for (int i = bstart + (int)threadIdx.x; i < bend; i += blockDim.x)
            atomicAdd(&cnt[(pcode_u[i].x >> 17) & 63], 1);
    }
    __syncthreads();
    if (threadIdx.x == 0) {
        int s = 0;
#pragma unroll
        for (int i = 0; i < 64; ++i) { off[i] = s; s += cnt[i]; }
    }
    __syncthreads();

    if (!is_u) {
        const int h0 = b * 64;
        if (threadIdx.x < 64) {
            const int h = h0 + (int)threadIdx.x;
            if (h < n_entities) offs_e[h] = bstart + off[threadIdx.x];
        }
        if (b == nbe - 1 && threadIdx.x == 0) offs_e[n_entities] = bend;
        for (int i = bstart + (int)threadIdx.x; i < bend; i += blockDim.x) {
            const int p  = pcode_e[i];
            const int lh = (p >> 22) & 63;
            const int pos = bstart + off[lh] + atomicAdd(&cur[lh], 1);
            sorted_tr[pos] = p & 0x3FFFFF;
        }
    } else {
        const int u0 = b * 64;
        if (threadIdx.x < 64) {
            const int u = u0 + (int)threadIdx.x;
            if (u < n_users) offs_u[u] = bstart + off[threadIdx.x];
        }
        if (b == nbu - 1 && threadIdx.x == 0) offs_u[n_users] = bend;
        for (int i = bstart + (int)threadIdx.x; i < bend; i += blockDim.x) {
            const uint2 cv = pcode_u[i];
            const int lr = (int)(cv.x >> 17) & 63;
            const int pos = bstart + off[lr] + atomicAdd(&cur[lr], 1);
            uint2 o;
            o.x = cv.x & 0x1FFFFu;
            o.y = cv.y;
            upack[pos] = o;
        }
    }
}

// =========================================================================
// Fused bf16 gathers (R26-proven): blocks [0,nwe) entities, rest users.
// =========================================================================
__global__ void gather2_kernel(const ushort_t* __restrict__ ebf,
                               const int* __restrict__ sorted_tr,
                               const int* __restrict__ offs_e,
                               const float* __restrict__ weight,
                               float* __restrict__ out_ent,
                               int n_entities, int n_rel, int nwe,
                               const uint2* __restrict__ upack,
                               const int* __restrict__ offs_u,
                               float* __restrict__ out_user,
                               int n_users) {
    extern __shared__ float wl[];   // n_rel * CH (entity blocks only)
    const int lane = threadIdx.x & 63;
    const int g    = lane >> 3;     // edge slot 0..7
    const int q8   = lane & 7;      // channel octet 0..7

    if ((int)blockIdx.x < nwe) {
        for (int i = threadIdx.x; i < n_rel * CH; i += blockDim.x) wl[i] = weight[i];
        __syncthreads();
        const float4* wl4 = reinterpret_cast<const float4*>(wl);

        const int wid = (blockIdx.x * blockDim.x + threadIdx.x) >> 6;
        if (wid >= n_entities) return;

        const int s0 = offs_e[wid], s1 = offs_e[wid + 1];
        float a0[8], a1[8];
#pragma unroll
        for (int j = 0; j < 8; ++j) { a0[j] = 0.f; a1[j] = 0.f; }

        int base = s0;
        for (; base + 16 <= s1; base += 16) {
            const int tr0 = sorted_tr[base + g];
            const int tr1 = sorted_tr[base + 8 + g];
            const uint4 p0 = *reinterpret_cast<const uint4*>(
                ebf + (size_t)(tr0 & 0x1FFFF) * CH + q8 * 8);
            const uint4 p1 = *reinterpret_cast<const uint4*>(
                ebf + (size_t)(tr1 & 0x1FFFF) * CH + q8 * 8);
            const float4 w0a = wl4[(tr0 >> 17) * 16 + q8 * 2];
            const float4 w0b = wl4[(tr0 >> 17) * 16 + q8 * 2 + 1];
            const float4 w1a = wl4[(tr1 >> 17) * 16 + q8 * 2];
            const float4 w1b = wl4[(tr1 >> 17) * 16 + q8 * 2 + 1];
            a0[0] = fmaf(bf_lo(p0.x), w0a.x, a0[0]);
            a0[1] = fmaf(bf_hi(p0.x), w0a.y, a0[1]);
            a0[2] = fmaf(bf_lo(p0.y), w0a.z, a0[2]);
            a0[3] = fmaf(bf_hi(p0.y), w0a.w, a0[3]);
            a0[4] = fmaf(bf_lo(p0.z), w0b.x, a0[4]);
            a0[5] = fmaf(bf_hi(p0.z), w0b.y, a0[5]);
            a0[6] = fmaf(bf_lo(p0.w), w0b.z, a0[6]);
            a0[7] = fmaf(bf_hi(p0.w), w0b.w, a0[7]);
            a1[0] = fmaf(bf_lo(p1.x), w1a.x, a1[0]);
            a1[1] = fmaf(bf_hi(p1.x), w1a.y, a1[1]);
            a1[2] = fmaf(bf_lo(p1.y), w1a.z, a1[2]);
            a1[3] = fmaf(bf_hi(p1.y), w1a.w, a1[3]);
            a1[4] = fmaf(bf_lo(p1.z), w1b.x, a1[4]);
            a1[5] = fmaf(bf_hi(p1.z), w1b.y, a1[5]);
            a1[6] = fmaf(bf_lo(p1.w), w1b.z, a1[6]);
            a1[7] = fmaf(bf_hi(p1.w), w1b.w, a1[7]);
        }
        for (; base < s1; base += 8) {
            const int e = base + g;
            const bool valid = (e < s1);
            const int tr = valid ? sorted_tr[e] : 0;
            uint4 p; p.x = 0u; p.y = 0u; p.z = 0u; p.w = 0u;
            if (valid)
                p = *reinterpret_cast<const uint4*>(
                    ebf + (size_t)(tr & 0x1FFFF) * CH + q8 * 8);
            const float4 wa = wl4[(tr >> 17) * 16 + q8 * 2];
            const float4 wb = wl4[(tr >> 17) * 16 + q8 * 2 + 1];
            a0[0] = fmaf(bf_lo(p.x), wa.x, a0[0]);
            a0[1] = fmaf(bf_hi(p.x), wa.y, a0[1]);
            a0[2] = fmaf(bf_lo(p.y), wa.z, a0[2]);
            a0[3] = fmaf(bf_hi(p.y), wa.w, a0[3]);
            a0[4] = fmaf(bf_lo(p.z), wb.x, a0[4]);
            a0[5] = fmaf(bf_hi(p.z), wb.y, a0[5]);
            a0[6] = fmaf(bf_lo(p.w), wb.z, a0[6]);
            a0[7] = fmaf(bf_hi(p.w), wb.w, a0[7]);
        }
#pragma unroll
        for (int j = 0; j < 8; ++j) a0[j] += a1[j];

#pragma unroll
        for (int j = 0; j < 8; ++j) {
            a0[j] += __shfl_xor(a0[j], 8);
            a0[j] += __shfl_xor(a0[j], 16);
            a0[j] += __shfl_xor(a0[j], 32);
        }

        if (g == 0) {
            const int deg = s1 - s0;
            const float inv = 1.0f / (float)(deg > 0 ? deg : 1);
            float4 o0, o1;
            o0.x = a0[0] * inv; o0.y = a0[1] * inv; o0.z = a0[2] * inv; o0.w = a0[3] * inv;
            o1.x = a0[4] * inv; o1.y = a0[5] * inv; o1.z = a0[6] * inv; o1.w = a0[7] * inv;
            float* op = out_ent + (size_t)wid * CH + q8 * 8;
            *reinterpret_cast<float4*>(op)     = o0;
            *reinterpret_cast<float4*>(op + 4) = o1;
        }
    } else {
        const int wid = ((blockIdx.x - nwe) * blockDim.x + threadIdx.x) >> 6;
        if (wid >= n_users) return;

        const int s0 = offs_u[wid], s1 = offs_u[wid + 1];
        float a0[8], a1[8];
#pragma unroll
        for (int j = 0; j < 8; ++j) { a0[j] = 0.f; a1[j] = 0.f; }

        int base = s0;
        for (; base + 16 <= s1; base += 16) {
            const uint2 cv0 = upack[base + g];
            const uint2 cv1 = upack[base + 8 + g];
            const float v0 = __uint_as_float(cv0.y);
            const float v1 = __uint_as_float(cv1.y);
            const uint4 p0 = *reinterpret_cast<const uint4*>(
                ebf + (size_t)cv0.x * CH + q8 * 8);
            const uint4 p1 = *reinterpret_cast<const uint4*>(
                ebf + (size_t)cv1.x * CH + q8 * 8);
            a0[0] = fmaf(v0, bf_lo(p0.x), a0[0]);
            a0[1] = fmaf(v0, bf_hi(p0.x), a0[1]);
            a0[2] = fmaf(v0, bf_lo(p0.y), a0[2]);
            a0[3] = fmaf(v0, bf_hi(p0.y), a0[3]);
            a0[4] = fmaf(v0, bf_lo(p0.z), a0[4]);
            a0[5] = fmaf(v0, bf_hi(p0.z), a0[5]);
            a0[6] = fmaf(v0, bf_lo(p0.w), a0[6]);
            a0[7] = fmaf(v0, bf_hi(p0.w), a0[7]);
            a1[0] = fmaf(v1, bf_lo(p1.x), a1[0]);
            a1[1] = fmaf(v1, bf_hi(p1.x), a1[1]);
            a1[2] = fmaf(v1, bf_lo(p1.y), a1[2]);
            a1[3] = fmaf(v1, bf_hi(p1.y), a1[3]);
            a1[4] = fmaf(v1, bf_lo(p1.z), a1[4]);
            a1[5] = fmaf(v1, bf_hi(p1.z), a1[5]);
            a1[6] = fmaf(v1, bf_lo(p1.w), a1[6]);
            a1[7] = fmaf(v1, bf_hi(p1.w), a1[7]);
        }
        for (; base < s1; base += 8) {
            const int e = base + g;
            const bool valid = (e < s1);
            uint2 cv; cv.x = 0u; cv.y = 0u;
            if (valid) cv = upack[e];
            const float v = __uint_as_float(cv.y);   // 0 when invalid
            const uint4 p = *reinterpret_cast<const uint4*>(
                ebf + (size_t)cv.x * CH + q8 * 8);   // row 0 valid memory
            a0[0] = fmaf(v, bf_lo(p.x), a0[0]);
            a0[1] = fmaf(v, bf_hi(p.x), a0[1]);
            a0[2] = fmaf(v, bf_lo(p.y), a0[2]);
            a0[3] = fmaf(v, bf_hi(p.y), a0[3]);
            a0[4] = fmaf(v, bf_lo(p.z), a0[4]);
            a0[5] = fmaf(v, bf_hi(p.z), a0[5]);
            a0[6] = fmaf(v, bf_lo(p.w), a0[6]);
            a0[7] = fmaf(v, bf_hi(p.w), a0[7]);
        }
#pragma unroll
        for (int j = 0; j < 8; ++j) a0[j] += a1[j];

#pragma unroll
        for (int j = 0; j < 8; ++j) {
            a0[j] += __shfl_xor(a0[j], 8);
            a0[j] += __shfl_xor(a0[j], 16);
            a0[j] += __shfl_xor(a0[j], 32);
        }

        if (g == 0) {
            float4 o0, o1;
            o0.x = a0[0]; o0.y = a0[1]; o0.z = a0[2]; o0.w = a0[3];
            o1.x = a0[4]; o1.y = a0[5]; o1.z = a0[6]; o1.w = a0[7];
            float* op = out_user + (size_t)wid * CH + q8 * 8;
            *reinterpret_cast<float4*>(op)     = o0;
            *reinterpret_cast<float4*>(op + 4) = o1;
        }
    }
}

// =========================================================================
// Tier-2 (CSR path): sliced hist/scatter
// =========================================================================
__global__ void hist_sliced_kernel(const int* __restrict__ keys,
                                   int* __restrict__ counts, int n, unsigned smul) {
    const int slice = blockIdx.x & (NSLICE - 1);
    const int rb    = blockIdx.x >> 3;
    const int nrb   = gridDim.x >> 3;
    const int per   = (n + nrb - 1) / nrb;
    const int i0    = rb * per;
    const int i1    = min(i0 + per, n);
    for (int i = i0 + (int)threadIdx.x; i < i1; i += blockDim.x) {
        const int k = keys[i];
        if ((int)__umulhi((unsigned)k, smul) == slice)
            atomicAdd(&counts[k], 1);
    }
}

__global__ void scatter_e_sliced_kernel(const int* __restrict__ edge_index,
                                        const int* __restrict__ edge_type,
                                        const int* __restrict__ offs,
                                        int* __restrict__ cursor,
                                        int* __restrict__ sorted_tr,
                                        int E, int n_rel, unsigned smul) {
    const int slice = blockIdx.x & (NSLICE - 1);
    const int rb    = blockIdx.x >> 3;
    const int nrb   = gridDim.x >> 3;
    const int per   = (E + nrb - 1) / nrb;
    const int e0    = rb * per;
    const int e1    = min(e0 + per, E);
    for (int e = e0 + (int)threadIdx.x; e < e1; e += blockDim.x) {
        const int h = edge_index[e];
        if ((int)__umulhi((unsigned)h, smul) != slice) continue;
        const int t = edge_index[(size_t)E + e];
        int r = edge_type[e] - 1;
        if (r < 0) r += n_rel;
        const int pos = offs[h] + atomicAdd(&cursor[h], 1);
        sorted_tr[pos] = t | (r << 17);
    }
}

__global__ void scatter_u_sliced_kernel(const int* __restrict__ irows,
                                        const int* __restrict__ icols,
                                        const float* __restrict__ ivals,
                                        const int* __restrict__ offs,
                                        int* __restrict__ cursor,
                                        uint2* __restrict__ upack,
                                        int NNZ, unsigned smul) {
    const int slice = blockIdx.x & (NSLICE - 1);
    const int rb    = blockIdx.x >> 3;
    const int nrb   = gridDim.x >> 3;
    const int per   = (NNZ + nrb - 1) / nrb;
    const int i0    = rb * per;
    const int i1    = min(i0 + per, NNZ);
    for (int i = i0 + (int)threadIdx.x; i < i1; i += blockDim.x) {
        const int u = irows[i];
        if ((int)__umulhi((unsigned)u, smul) != slice) continue;
        const int pos = offs[u] + atomicAdd(&cursor[u], 1);
        uint2 cv;
        cv.x = (unsigned)icols[i];
        cv.y = __float_as_uint(ivals[i]);
        upack[pos] = cv;
    }
}

// =========================================================================
// Tier-3 (atomic fallback)
// =========================================================================
__global__ void kg_agg_atomic_kernel(const float* __restrict__ emb,
                                     const float* __restrict__ region_ent,
                                     const int* __restrict__ edge_index,
                                     const int* __restrict__ edge_type,
                                     const float* __restrict__ weight,
                                     float* __restrict__ out_ent,
                                     float* __restrict__ counts,
                                     int E, int n_rel) {
    const long long gid = (long long)blockIdx.x * blockDim.x + threadIdx.x;
    const long long e = gid >> 6;
    if (e >= E) return;
    const int c = (int)gid & 63;
    const int h = edge_index[e];
    const int t = edge_index[(size_t)E + e];
    int r = edge_type[e] - 1;
    if (r < 0) r += n_rel;
    const float v = ent_val(emb, region_ent, t, c) * weight[(size_t)r * CH + c];
    unsafeAtomicAdd(out_ent + (size_t)h * CH + c, v);
    if (c == 0) unsafeAtomicAdd(counts + h, 1.0f);
}

__global__ void user_agg_atomic_kernel(const float* __restrict__ emb,
                                       const float* __restrict__ region_ent,
                                       const int* __restrict__ irows,
                                       const int* __restrict__ icols,
                                       const float* __restrict__ ivals,
                                       float* __restrict__ out_user, int NNZ) {
    const long long gid = (long long)blockIdx.x * blockDim.x + threadIdx.x;
    const long long i = gid >> 6;
    if (i >= NNZ) return;
    const int c = (int)gid & 63;
    const float v = ivals[i] * ent_val(emb, region_ent, icols[i], c);
    unsafeAtomicAdd(out_user + (size_t)irows[i] * CH + c, v);
}

__global__ void finalize_kernel(float* __restrict__ out_ent,
                                const float* __restrict__ counts, int n_entities) {
    const int gid = blockIdx.x * blockDim.x + threadIdx.x;
    if (gid >= n_entities * CH) return;
    out_ent[gid] /= fmaxf(counts[gid >> 6], 1.0f);
}

// =========================================================================
extern "C" void kernel_launch(void* const* d_in, const int* in_sizes, int n_in,
                              void* d_out, int out_size, void* d_ws, size_t ws_size,
                              hipStream_t stream) {
    const float* entity_emb = (const float*)d_in[0];
    const int*   edge_index = (const int*)d_in[2];
    const int*   edge_type  = (const int*)d_in[3];
    const int*   irows      = (const int*)d_in[4];
    const int*   icols      = (const int*)d_in[5];
    const float* ivals      = (const float*)d_in[6];
    const float* Wreg       = (const float*)d_in[7];
    const float* weight     = (const float*)d_in[8];

    const int n_entities = in_sizes[0] / CH;
    const int n_users    = in_sizes[1] / CH;
    const int E          = in_sizes[3];
    const int NNZ        = in_sizes[4];
    const int n_rel      = in_sizes[8] / CH;

    float* out_ent  = (float*)d_out;
    float* out_user = out_ent + (size_t)n_entities * CH;

    const int NBUK_E = (n_entities + 63) >> 6;
    const int NBUK_U = (n_users + 63) >> 6;
    const int n_e = NBUK_E * NB;
    const int n_u = NBUK_U * NB;
    const int nbse = (n_e + SCAN_B - 1) / SCAN_B;
    const int nbsu = (n_u + SCAN_B - 1) / SCAN_B;

    // ---- tier-1 (bucket) layout ----
    char* w = (char*)d_ws;
    auto take = [&](size_t bytes) {
        char* p = w;
        w += (bytes + 7) & ~(size_t)7;
        return p;
    };
    float*    region_ent = (float*)take((size_t)RN * CH * 4);
    ushort_t* e_t        = (ushort_t*)take((size_t)CH * KP * 2);
    ushort_t* ebf        = (ushort_t*)take((size_t)n_entities * CH * 2);
    int*      sorted_tr  = (int*)take((size_t)E * 4);
    uint2*    upack      = (uint2*)take((size_t)NNZ * 8);
    int*      offs_e     = (int*)take((size_t)(n_entities + 1) * 4);
    int*      offs_u     = (int*)take((size_t)(n_users + 1) * 4);
    int*      bsums_e    = (int*)take(512 * 4);
    int*      bsums_u    = (int*)take(512 * 4);
    int*      hist_e     = (int*)take((size_t)n_e * 4);
    int*      exbase_e   = (int*)take((size_t)(n_e + 1) * 4);
    int*      hist_u     = (int*)take((size_t)n_u * 4);
    int*      exbase_u   = (int*)take((size_t)(n_u + 1) * 4);
    int*      pcode_e    = (int*)take((size_t)E * 4);
    uint2*    pcode_u    = (uint2*)take((size_t)NNZ * 8);
    const size_t need_bucket = (size_t)(w - (char*)d_ws);

    const bool common_ok = (n_entities < (1 << 17)) && (n_rel <= 32);
    const bool use_bucket = common_ok && (ws_size >= need_bucket) &&
                            (NBUK_E <= MAXBUK) && (NBUK_U <= MAXBUK) &&
                            (nbse <= 512) && (nbsu <= 512);

    // ---- tier-2 (csr) layout ----
    char* w2 = (char*)d_ws;
    auto take2 = [&](size_t bytes) {
        char* p = w2;
        w2 += (bytes + 7) & ~(size_t)7;
        return p;
    };
    float*    c_region  = (float*)take2((size_t)RN * CH * 4);
    int*      c_offs_e  = (int*)take2((size_t)(n_entities + 1) * 4);
    int*      c_cur_e   = (int*)take2((size_t)n_entities * 4);
    int*      c_offs_u  = (int*)take2((size_t)(n_users + 1) * 4);
    int*      c_cur_u   = (int*)take2((size_t)n_users * 4);
    int*      c_bsums   = (int*)take2(512 * 4);
    int*      c_sorted  = (int*)take2((size_t)E * 4);
    uint2*    c_upack   = (uint2*)take2((size_t)NNZ * 8);
    ushort_t* c_et      = (ushort_t*)take2((size_t)CH * KP * 2);
    ushort_t* c_ebf     = (ushort_t*)take2((size_t)n_entities * CH * 2);
    const size_t need_csr = (size_t)(w2 - (char*)d_ws);
    const int nb_e = (n_entities + SCAN_B - 1) / SCAN_B;
    const int nb_u = (n_users + SCAN_B - 1) / SCAN_B;
    const bool use_csr = common_ok && (ws_size >= need_csr) &&
                         (nb_e <= 512) && (nb_u <= 512);

    const int nwe = (n_entities + 3) / 4;
    const int nwu = (n_users + 3) / 4;

    if (use_bucket) {
        region_init_et_kernel<<<IB_INIT + EB_ET, 256, 0, stream>>>(
            entity_emb, region_ent, e_t);
        region_gemm_mfma_kernel<<<MT_BLKS * KCHUNKS, 256, 0, stream>>>(
            Wreg, e_t, region_ent);
        {
            const int tot = n_entities * (CH / 8);
            build_ebf_kernel<<<(tot + 255) / 256, 256, 0, stream>>>(
                entity_emb, region_ent, ebf, n_entities);
        }

        bucket_hist2_kernel<<<2 * NB, T1, 0, stream>>>(
            edge_index, E, NBUK_E, irows, NNZ, NBUK_U, hist_e, hist_u);

        scan_block2_kernel<<<nbse + nbsu, SCAN_B, 0, stream>>>(
            hist_e, exbase_e, bsums_e, n_e, nbse,
            hist_u, exbase_u, bsums_u, n_u);
        scan_top2_kernel<<<2, 512, 0, stream>>>(bsums_e, nbse, bsums_u, nbsu);
        scan_add2_kernel<<<nbse + nbsu, SCAN_B, 0, stream>>>(
            exbase_e, bsums_e, n_e, nbse, exbase_u, bsums_u, n_u);

        pass2_combined_kernel<<<2 * NB, T1, 0, stream>>>(
            edge_index, edge_type, exbase_e, pcode_e, E, n_rel, NBUK_E,
            irows, icols, ivals, exbase_u, pcode_u, NNZ, NBUK_U);

        bucket_sort2_kernel<<<NBUK_E + NBUK_U, 256, 0, stream>>>(
            pcode_e, exbase_e, sorted_tr, offs_e, n_entities, NBUK_E,
            pcode_u, exbase_u, upack, offs_u, n_users, NBUK_U);

        gather2_kernel<<<nwe + nwu, 256, n_rel * CH * 4, stream>>>(
            ebf, sorted_tr, offs_e, weight, out_ent, n_entities, n_rel, nwe,
            upack, offs_u, out_user, n_users);
    } else if (use_csr) {
        const unsigned smul_e = (unsigned)((8ULL << 32) / (unsigned long long)n_entities);
        const unsigned smul_u = (unsigned)((8ULL << 32) / (unsigned long long)n_users);

        region_init_et_kernel<<<IB_INIT + EB_ET, 256, 0, stream>>>(
            entity_emb, c_region, c_et);
        region_gemm_mfma_kernel<<<MT_BLKS * KCHUNKS, 256, 0, stream>>>(
            Wreg, c_et, c_region);
        {
            const int tot = n_entities * (CH / 8);
            build_ebf_kernel<<<(tot + 255) / 256, 256, 0, stream>>>(
                entity_emb, c_region, c_ebf, n_entities);
        }

        hipMemsetAsync(c_cur_e, 0, (size_t)n_entities * 4, stream);
        hipMemsetAsync(c_cur_u, 0, (size_t)n_users * 4, stream);
        hist_sliced_kernel<<<NSLICE * SLICE_RB, 256, 0, stream>>>(
            edge_index, c_cur_e, E, smul_e);
        hist_sliced_kernel<<<NSLICE * SLICE_RB, 256, 0, stream>>>(
            irows, c_cur_u, NNZ, smul_u);

        scan_block_kernel<<<nb_e, SCAN_B, 0, stream>>>(c_cur_e, c_offs_e, c_bsums, n_entities);
        scan_top_kernel<<<1, 512, 0, stream>>>(c_bsums, nb_e);
        scan_add_kernel<<<nb_e, SCAN_B, 0, stream>>>(c_offs_e, c_bsums, n_entities);

        scan_block_kernel<<<nb_u, SCAN_B, 0, stream>>>(c_cur_u, c_offs_u, c_bsums, n_users);
        scan_top_kernel<<<1, 512, 0, stream>>>(c_bsums, nb_u);
        scan_add_kernel<<<nb_u, SCAN_B, 0, stream>>>(c_offs_u, c_bsums, n_users);

        hipMemsetAsync(c_cur_e, 0, (size_t)n_entities * 4, stream);
        hipMemsetAsync(c_cur_u, 0, (size_t)n_users * 4, stream);
        scatter_e_sliced_kernel<<<NSLICE * SLICE_RB, 256, 0, stream>>>(
            edge_index, edge_type, c_offs_e, c_cur_e, c_sorted, E, n_rel, smul_e);
        scatter_u_sliced_kernel<<<NSLICE * SLICE_RB, 256, 0, stream>>>(
            irows, icols, ivals, c_offs_u, c_cur_u, c_upack, NNZ, smul_u);

        gather2_kernel<<<nwe + nwu, 256, n_rel * CH * 4, stream>>>(
            c_ebf, c_sorted, c_offs_e, weight, out_ent, n_entities, n_rel, nwe,
            c_upack, c_offs_u, out_user, n_users);
    } else {
        // tier-3: atomic fallback
        float* region3 = (float*)d_ws;
        float* counts  = region3 + (size_t)RN * CH;
        region_init_kernel<<<(RN * CH / 4 + 255) / 256, 256, 0, stream>>>(entity_emb, region3);
        region_gemm_kernel<<<ROW_TILES * KSPLIT, 256, 0, stream>>>(
            entity_emb, Wreg, region3);
        hipMemsetAsync(d_out, 0, (size_t)out_size * sizeof(float), stream);
        hipMemsetAsync(counts, 0, (size_t)n_entities * sizeof(float), stream);
        {
            const long long tot = (long long)E * CH;
            kg_agg_atomic_kernel<<<(int)((tot + 255) / 256), 256, 0, stream>>>(
                entity_emb, region3, edge_index, edge_type, weight,
                out_ent, counts, E, n_rel);
        }
        {
            const long long tot = (long long)NNZ * CH;
            user_agg_atomic_kernel<<<(int)((tot + 255) / 256), 256, 0, stream>>>(
                entity_emb, region3, irows, icols, ivals, out_user, NNZ);
        }
        finalize_kernel<<<(n_entities * CH + 255) / 256, 256, 0, stream>>>(
            out_ent, counts, n_entities);
    }
}